// Round 1
// baseline (864.239 us; speedup 1.0000x reference)
//
#include <hip/hip_runtime.h>

// DiscoDownBlock: GN1 -> 1x1 MLP (expand/gelu/project) + residual -> DISCO S2 conv
//                 -> GN2 -> gelu.  Outputs: skip [2,128,181,360], x_down [2,256,91,180]
//
// Round 1: correctness-first fp32-vector implementation.
//  - GN stats via deterministic 2-stage tree reductions (no float atomics).
//  - MLP fused per 64-pixel tile: xn (bf16) and h1 (bf16) staged in LDS (49 KB).
//  - DISCO: per (b,ho,16-wo) tile; gather is n-indexed only (shared across k),
//    y staged bf16 in LDS, weight chunk staged fp32 (63 KB total LDS).
//  - GN2 partials -> finalize -> in-place gelu epilogue.

#define HW      65160      // 181*360
#define HIN     181
#define WIN     360
#define HOUT    91
#define WOUT    180
#define CIN     128
#define COUT    256
#define KB      7
#define NNZ     16
#define N_GN1   1042560    // 16*HW
#define N_GN2   524160     // 32*91*180
#define NT_D    1092       // 91 * 12 wo-tiles

__device__ __forceinline__ unsigned short f2b(float v){
    unsigned u = __float_as_uint(v);
    u += 0x7fffu + ((u >> 16) & 1u);          // round-to-nearest-even
    return (unsigned short)(u >> 16);
}
__device__ __forceinline__ float blo(unsigned u){ return __uint_as_float(u << 16); }
__device__ __forceinline__ float bhi(unsigned u){ return __uint_as_float(u & 0xffff0000u); }

// tanh-approx gelu (matches jax.nn.gelu approximate=True), overflow-safe
__device__ __forceinline__ float gelu_f(float v){
    float z  = 0.7978845608028654f * (v + 0.044715f * v * v * v);
    float az = fabsf(z);
    float e  = __expf(-2.0f * az);            // in (0,1], no overflow
    float th = (1.0f - e) / (1.0f + e);
    th = copysignf(th, z);
    return 0.5f * v * (1.0f + th);
}

// ---------------- GN1 stats ----------------
__global__ __launch_bounds__(256) void k_gn1_partial(const float* __restrict__ x,
                                                     float* __restrict__ part){
    const int bg = blockIdx.y, blk = blockIdx.x, t = threadIdx.x;
    const float4* p4 = (const float4*)(x + (size_t)bg * N_GN1);
    float s = 0.f, ss = 0.f;
    for (int v = blk*256 + t; v < N_GN1/4; v += 128*256){
        float4 q = p4[v];
        s  += q.x + q.y + q.z + q.w;
        ss += q.x*q.x + q.y*q.y + q.z*q.z + q.w*q.w;
    }
    #pragma unroll
    for (int off = 32; off; off >>= 1){ s += __shfl_down(s, off); ss += __shfl_down(ss, off); }
    __shared__ float ls[4][2];
    if ((t & 63) == 0){ ls[t>>6][0] = s; ls[t>>6][1] = ss; }
    __syncthreads();
    if (t == 0){
        s  = ls[0][0] + ls[1][0] + ls[2][0] + ls[3][0];
        ss = ls[0][1] + ls[1][1] + ls[2][1] + ls[3][1];
        part[(bg*128 + blk)*2]     = s;
        part[(bg*128 + blk)*2 + 1] = ss;
    }
}

__global__ __launch_bounds__(128) void k_gn1_final(const float* __restrict__ part,
                                                   float* __restrict__ stat){
    const int bg = blockIdx.x, t = threadIdx.x;
    float s  = part[(bg*128 + t)*2];
    float ss = part[(bg*128 + t)*2 + 1];
    #pragma unroll
    for (int off = 32; off; off >>= 1){ s += __shfl_down(s, off); ss += __shfl_down(ss, off); }
    __shared__ float ls[2][2];
    if ((t & 63) == 0){ ls[t>>6][0] = s; ls[t>>6][1] = ss; }
    __syncthreads();
    if (t == 0){
        s  = ls[0][0] + ls[1][0];
        ss = ls[0][1] + ls[1][1];
        float m = s / (float)N_GN1;
        float v = ss / (float)N_GN1 - m*m;
        stat[bg*2]     = m;
        stat[bg*2 + 1] = 1.0f / sqrtf(v + 1e-5f);
    }
}

// ---------------- fused MLP + residual ----------------
// grid (1019, 2), 256 thr.  64-pixel tile.  LDS: xn bf16 [128][64], h1 bf16 [256][64].
__global__ __launch_bounds__(256) void k_mlp(
    const float* __restrict__ x, const float* __restrict__ stat,
    const float* __restrict__ g1, const float* __restrict__ be1,
    const float* __restrict__ w1, const float* __restrict__ b1,
    const float* __restrict__ w2, const float* __restrict__ b2,
    float* __restrict__ skip)
{
    __shared__ unsigned short xns[128*64];
    __shared__ unsigned short h1s[256*64];
    const int t = threadIdx.x;
    const int b = blockIdx.y;
    const int pix0 = blockIdx.x * 64;
    int valid = HW - pix0; if (valid > 64) valid = 64;

    { // stage normalized input tile
        const int p = t & 63, cq = t >> 6;
        for (int c = cq; c < 128; c += 4){
            float v = 0.f;
            if (p < valid){
                float m = stat[(b*8 + (c >> 4))*2];
                float r = stat[(b*8 + (c >> 4))*2 + 1];
                v = (x[(size_t)(b*128 + c)*HW + pix0 + p] - m) * r * g1[c] + be1[c];
            }
            xns[c*64 + p] = f2b(v);
        }
    }
    __syncthreads();

    const int oq = t >> 4, pq = t & 15;

    // GEMM1: h1 = gelu(w1 @ xn + b1), 4 chunks of 64 output channels
    #pragma unroll 1
    for (int ch = 0; ch < 4; ++ch){
        const int ob = ch*64 + oq*4;
        float acc[4][4];
        #pragma unroll
        for (int i = 0; i < 4; ++i){
            float bv = b1[ob + i];
            #pragma unroll
            for (int j = 0; j < 4; ++j) acc[i][j] = bv;
        }
        const float* wr0 = w1 + (size_t)(ob+0)*128;
        const float* wr1 = w1 + (size_t)(ob+1)*128;
        const float* wr2 = w1 + (size_t)(ob+2)*128;
        const float* wr3 = w1 + (size_t)(ob+3)*128;
        #pragma unroll 4
        for (int c = 0; c < 128; ++c){
            uint2 q = *(const uint2*)(&xns[c*64 + pq*4]);
            float x0 = blo(q.x), x1 = bhi(q.x), x2 = blo(q.y), x3 = bhi(q.y);
            float w0v = wr0[c], w1v = wr1[c], w2v = wr2[c], w3v = wr3[c];
            acc[0][0] += w0v*x0; acc[0][1] += w0v*x1; acc[0][2] += w0v*x2; acc[0][3] += w0v*x3;
            acc[1][0] += w1v*x0; acc[1][1] += w1v*x1; acc[1][2] += w1v*x2; acc[1][3] += w1v*x3;
            acc[2][0] += w2v*x0; acc[2][1] += w2v*x1; acc[2][2] += w2v*x2; acc[2][3] += w2v*x3;
            acc[3][0] += w3v*x0; acc[3][1] += w3v*x1; acc[3][2] += w3v*x2; acc[3][3] += w3v*x3;
        }
        #pragma unroll
        for (int i = 0; i < 4; ++i){
            float g0 = gelu_f(acc[i][0]), g1v = gelu_f(acc[i][1]);
            float g2v = gelu_f(acc[i][2]), g3v = gelu_f(acc[i][3]);
            uint2 pk;
            pk.x = (unsigned)f2b(g0)  | ((unsigned)f2b(g1v) << 16);
            pk.y = (unsigned)f2b(g2v) | ((unsigned)f2b(g3v) << 16);
            *(uint2*)(&h1s[(ob+i)*64 + pq*4]) = pk;
        }
    }
    __syncthreads();

    // GEMM2: skip = w2 @ h1 + b2 + x, 2 chunks of 64 output channels
    #pragma unroll 1
    for (int ch = 0; ch < 2; ++ch){
        const int ob = ch*64 + oq*4;
        float acc[4][4];
        #pragma unroll
        for (int i = 0; i < 4; ++i){
            float bv = b2[ob + i];
            #pragma unroll
            for (int j = 0; j < 4; ++j) acc[i][j] = bv;
        }
        const float* wr0 = w2 + (size_t)(ob+0)*256;
        const float* wr1 = w2 + (size_t)(ob+1)*256;
        const float* wr2p = w2 + (size_t)(ob+2)*256;
        const float* wr3 = w2 + (size_t)(ob+3)*256;
        #pragma unroll 4
        for (int k = 0; k < 256; ++k){
            uint2 q = *(const uint2*)(&h1s[k*64 + pq*4]);
            float x0 = blo(q.x), x1 = bhi(q.x), x2 = blo(q.y), x3 = bhi(q.y);
            float w0v = wr0[k], w1v = wr1[k], w2v = wr2p[k], w3v = wr3[k];
            acc[0][0] += w0v*x0; acc[0][1] += w0v*x1; acc[0][2] += w0v*x2; acc[0][3] += w0v*x3;
            acc[1][0] += w1v*x0; acc[1][1] += w1v*x1; acc[1][2] += w1v*x2; acc[1][3] += w1v*x3;
            acc[2][0] += w2v*x0; acc[2][1] += w2v*x1; acc[2][2] += w2v*x2; acc[2][3] += w2v*x3;
            acc[3][0] += w3v*x0; acc[3][1] += w3v*x1; acc[3][2] += w3v*x2; acc[3][3] += w3v*x3;
        }
        const int p = pq*4;
        #pragma unroll
        for (int i = 0; i < 4; ++i){
            if (p + 3 < valid){
                const int cc = ob + i;
                size_t base = (size_t)(b*128 + cc)*HW + pix0 + p;
                float4 xv = *(const float4*)(x + base);
                float4 o;
                o.x = acc[i][0] + xv.x; o.y = acc[i][1] + xv.y;
                o.z = acc[i][2] + xv.z; o.w = acc[i][3] + xv.w;
                *(float4*)(skip + base) = o;
            }
        }
    }
}

// ---------------- DISCO conv + GN2 partials ----------------
// grid (12, 91, 2), 256 thr.  wo-tile = 16.
__global__ __launch_bounds__(256) void k_disco(
    const float* __restrict__ skip,
    const float* __restrict__ psi_v, const int* __restrict__ psi_hi, const int* __restrict__ psi_wi,
    const float* __restrict__ weight, const float* __restrict__ bias,
    float* __restrict__ xdown, float* __restrict__ part)
{
    __shared__ float psis[112];          // [k][n]
    __shared__ int   offh[16];
    __shared__ int   wis[16];
    __shared__ unsigned short ylds[896*16];  // bf16 [c*7+k][wo]
    __shared__ float wch[256*33];            // fp32 weight chunk [co][32 ck], padded

    const int t  = threadIdx.x;
    const int wt = blockIdx.x, ho = blockIdx.y, b = blockIdx.z;
    const int wob = wt * 16;

    if (t < 112) psis[t] = psi_v[((t >> 4)*HOUT + ho)*NNZ + (t & 15)];
    if (t < 16){ offh[t] = psi_hi[ho*NNZ + t] * WIN; wis[t] = psi_wi[ho*NNZ + t]; }
    __syncthreads();

    { // y build: each thread owns (4 channels, 1 wo); gather shared across k
        const int wl = t & 15, cq = t >> 4;
        const int wo2 = 2*(wob + wl);
        #pragma unroll 1
        for (int cb = 0; cb < 2; ++cb){
            const int c0 = cb*64 + cq*4;
            const float* r0 = skip + (size_t)(b*128 + c0)*HW;
            float yk[4][7];
            #pragma unroll
            for (int cc = 0; cc < 4; ++cc)
                #pragma unroll
                for (int k = 0; k < 7; ++k) yk[cc][k] = 0.f;
            #pragma unroll 4
            for (int n = 0; n < 16; ++n){
                int w = wis[n] + wo2;
                w = (w >= 720) ? (w - 720) : (w >= 360 ? (w - 360) : w);
                const int off = offh[n] + w;
                float ga = r0[off];
                float gb = r0[off + HW];
                float gc = r0[off + 2*HW];
                float gd = r0[off + 3*HW];
                #pragma unroll
                for (int k = 0; k < 7; ++k){
                    float pv = psis[k*16 + n];
                    yk[0][k] += pv*ga; yk[1][k] += pv*gb; yk[2][k] += pv*gc; yk[3][k] += pv*gd;
                }
            }
            #pragma unroll
            for (int cc = 0; cc < 4; ++cc)
                #pragma unroll
                for (int k = 0; k < 7; ++k)
                    ylds[((c0+cc)*7 + k)*16 + wl] = f2b(yk[cc][k]);
        }
    }

    // contraction: out[co][wo] = sum_ck weight[co][ck] * y[ck][wo]
    const int oq = t >> 2, wq = t & 3;
    const int ob = oq*4;
    float acc[4][4];
    #pragma unroll
    for (int i = 0; i < 4; ++i)
        #pragma unroll
        for (int j = 0; j < 4; ++j) acc[i][j] = 0.f;

    #pragma unroll 1
    for (int kch = 0; kch < 28; ++kch){
        __syncthreads();           // protect wch reuse; first iter also fences ylds writes
        const int ckb = kch*32;
        {
            const int ckl = t & 31, co2 = t >> 5;
            #pragma unroll 8
            for (int it = 0; it < 32; ++it){
                int co = (it << 3) + co2;
                wch[co*33 + ckl] = weight[(size_t)co*896 + ckb + ckl];
            }
        }
        __syncthreads();
        #pragma unroll 4
        for (int ckl = 0; ckl < 32; ++ckl){
            uint2 q = *(const uint2*)(&ylds[(ckb + ckl)*16 + wq*4]);
            float y0 = blo(q.x), y1 = bhi(q.x), y2 = blo(q.y), y3 = bhi(q.y);
            float w0v = wch[(ob+0)*33 + ckl];
            float w1v = wch[(ob+1)*33 + ckl];
            float w2v = wch[(ob+2)*33 + ckl];
            float w3v = wch[(ob+3)*33 + ckl];
            acc[0][0] += w0v*y0; acc[0][1] += w0v*y1; acc[0][2] += w0v*y2; acc[0][3] += w0v*y3;
            acc[1][0] += w1v*y0; acc[1][1] += w1v*y1; acc[1][2] += w1v*y2; acc[1][3] += w1v*y3;
            acc[2][0] += w2v*y0; acc[2][1] += w2v*y1; acc[2][2] += w2v*y2; acc[2][3] += w2v*y3;
            acc[3][0] += w3v*y0; acc[3][1] += w3v*y1; acc[3][2] += w3v*y2; acc[3][3] += w3v*y3;
        }
    }

    // bias + store + GN2 partial (mask wo >= 180; wo-groups are float4-whole)
    float s = 0.f, ss = 0.f;
    const int wo = wob + wq*4;
    #pragma unroll
    for (int i = 0; i < 4; ++i){
        if (wo + 3 < WOUT){
            float bv = bias[ob + i];
            float4 o;
            o.x = acc[i][0] + bv; o.y = acc[i][1] + bv;
            o.z = acc[i][2] + bv; o.w = acc[i][3] + bv;
            *(float4*)(xdown + ((size_t)(b*256 + ob + i)*HOUT + ho)*WOUT + wo) = o;
            s  += o.x + o.y + o.z + o.w;
            ss += o.x*o.x + o.y*o.y + o.z*o.z + o.w*o.w;
        }
    }
    #pragma unroll
    for (int off = 16; off; off >>= 1){
        s  += __shfl_down(s,  off, 32);
        ss += __shfl_down(ss, off, 32);
    }
    if ((t & 31) == 0){
        const int g2 = t >> 5;                 // == (ob >> 5)
        const int tile = ho*12 + wt;
        part[(((size_t)b*NT_D + tile)*8 + g2)*2]     = s;
        part[(((size_t)b*NT_D + tile)*8 + g2)*2 + 1] = ss;
    }
}

// ---------------- GN2 finalize ----------------
__global__ __launch_bounds__(256) void k_gn2_final(const float* __restrict__ part,
                                                   float* __restrict__ stat){
    const int bg = blockIdx.x, b = bg >> 3, g = bg & 7, t = threadIdx.x;
    float s = 0.f, ss = 0.f;
    for (int i = t; i < NT_D; i += 256){
        s  += part[(((size_t)b*NT_D + i)*8 + g)*2];
        ss += part[(((size_t)b*NT_D + i)*8 + g)*2 + 1];
    }
    #pragma unroll
    for (int off = 32; off; off >>= 1){ s += __shfl_down(s, off); ss += __shfl_down(ss, off); }
    __shared__ float ls[4][2];
    if ((t & 63) == 0){ ls[t>>6][0] = s; ls[t>>6][1] = ss; }
    __syncthreads();
    if (t == 0){
        s  = ls[0][0] + ls[1][0] + ls[2][0] + ls[3][0];
        ss = ls[0][1] + ls[1][1] + ls[2][1] + ls[3][1];
        float m = s / (float)N_GN2;
        float v = ss / (float)N_GN2 - m*m;
        stat[bg*2]     = m;
        stat[bg*2 + 1] = 1.0f / sqrtf(v + 1e-5f);
    }
}

// ---------------- GN2 apply + gelu (in place) ----------------
__global__ __launch_bounds__(256) void k_gn2_apply(float* __restrict__ xd,
                                                   const float* __restrict__ stat,
                                                   const float* __restrict__ g2a,
                                                   const float* __restrict__ be2){
    const int gid = blockIdx.x*256 + threadIdx.x;
    const int stride = gridDim.x*256;
    for (int v = gid; v < 2096640; v += stride){
        float4 q = ((float4*)xd)[v];
        int i  = v << 2;
        int bc = i / 16380;                 // (b*256 + co); 16380 = 91*180 (mult of 4)
        int co = bc & 255, b = bc >> 8;
        float m  = stat[(b*8 + (co >> 5))*2];
        float r  = stat[(b*8 + (co >> 5))*2 + 1];
        float ga = g2a[co], be = be2[co];
        q.x = gelu_f((q.x - m)*r*ga + be);
        q.y = gelu_f((q.y - m)*r*ga + be);
        q.z = gelu_f((q.z - m)*r*ga + be);
        q.w = gelu_f((q.w - m)*r*ga + be);
        ((float4*)xd)[v] = q;
    }
}

extern "C" void kernel_launch(void* const* d_in, const int* in_sizes, int n_in,
                              void* d_out, int out_size, void* d_ws, size_t ws_size,
                              hipStream_t stream){
    const float* x      = (const float*)d_in[0];
    const float* psi_v  = (const float*)d_in[1];
    const int*   psi_hi = (const int*)d_in[2];
    const int*   psi_wi = (const int*)d_in[3];
    const float* weight = (const float*)d_in[4];
    const float* bias   = (const float*)d_in[5];
    const float* g1     = (const float*)d_in[6];
    const float* be1    = (const float*)d_in[7];
    const float* w1     = (const float*)d_in[8];
    const float* b1     = (const float*)d_in[9];
    const float* w2     = (const float*)d_in[10];
    const float* b2     = (const float*)d_in[11];
    const float* g2     = (const float*)d_in[12];
    const float* be2    = (const float*)d_in[13];

    float* skip  = (float*)d_out;
    float* xdown = skip + 16680960;          // 2*128*181*360

    float* ws       = (float*)d_ws;
    float* gn1_part = ws;                    // 16*128*2 = 4096
    float* gn1_stat = ws + 4096;             // 32
    float* gn2_part = ws + 4128;             // 2*1092*8*2 = 34944
    float* gn2_stat = ws + 4128 + 34944;     // 32

    k_gn1_partial<<<dim3(128, 16), 256, 0, stream>>>(x, gn1_part);
    k_gn1_final  <<<16, 128, 0, stream>>>(gn1_part, gn1_stat);
    k_mlp        <<<dim3(1019, 2), 256, 0, stream>>>(x, gn1_stat, g1, be1, w1, b1, w2, b2, skip);
    k_disco      <<<dim3(12, 91, 2), 256, 0, stream>>>(skip, psi_v, psi_hi, psi_wi,
                                                       weight, bias, xdown, gn2_part);
    k_gn2_final  <<<16, 256, 0, stream>>>(gn2_part, gn2_stat);
    k_gn2_apply  <<<2048, 256, 0, stream>>>(xdown, gn2_stat, g2, be2);
}

// Round 2
// 505.522 us; speedup vs baseline: 1.7096x; 1.7096x over previous
//
#include <hip/hip_runtime.h>

// DiscoDownBlock: GN1 -> 1x1 MLP (expand/gelu/project) + residual -> DISCO S2 conv
//                 -> GN2 -> gelu.  Outputs: skip [2,128,181,360], x_down [2,256,91,180]
//
// Round 2: DISCO contraction moved to bf16 MFMA (16x16x32).
//  - k_wcvt pre-transposes weight [co][c][k] -> bf16 [co][k*128+c] in d_ws.
//  - k_disco: per (wo-half, ho, b, co-half) block; 4 c-chunks of 32:
//    gather+psi reduce in registers -> bf16 y tile in XOR-swizzled LDS ->
//    7 MFMA K-slices; 4 waves with 64co x 48wo tiles (4x3 fragments).
//  - GN2 partials per wave; k_gn2_final updated for new partial layout.

#define HW      65160      // 181*360
#define HIN     181
#define WIN     360
#define HOUT    91
#define WOUT    180
#define CIN     128
#define COUT    256
#define KB      7
#define NNZ     16
#define N_GN1   1042560    // 16*HW
#define N_GN2   524160     // 32*91*180

typedef float  f32x4  __attribute__((ext_vector_type(4)));
typedef __bf16 bf16x8 __attribute__((ext_vector_type(8)));

__device__ __forceinline__ unsigned short f2b(float v){
    unsigned u = __float_as_uint(v);
    u += 0x7fffu + ((u >> 16) & 1u);          // round-to-nearest-even
    return (unsigned short)(u >> 16);
}
__device__ __forceinline__ float blo(unsigned u){ return __uint_as_float(u << 16); }
__device__ __forceinline__ float bhi(unsigned u){ return __uint_as_float(u & 0xffff0000u); }

// tanh-approx gelu (matches jax.nn.gelu approximate=True), overflow-safe
__device__ __forceinline__ float gelu_f(float v){
    float z  = 0.7978845608028654f * (v + 0.044715f * v * v * v);
    float az = fabsf(z);
    float e  = __expf(-2.0f * az);            // in (0,1], no overflow
    float th = (1.0f - e) / (1.0f + e);
    th = copysignf(th, z);
    return 0.5f * v * (1.0f + th);
}

// ---------------- GN1 stats ----------------
__global__ __launch_bounds__(256) void k_gn1_partial(const float* __restrict__ x,
                                                     float* __restrict__ part){
    const int bg = blockIdx.y, blk = blockIdx.x, t = threadIdx.x;
    const float4* p4 = (const float4*)(x + (size_t)bg * N_GN1);
    float s = 0.f, ss = 0.f;
    for (int v = blk*256 + t; v < N_GN1/4; v += 128*256){
        float4 q = p4[v];
        s  += q.x + q.y + q.z + q.w;
        ss += q.x*q.x + q.y*q.y + q.z*q.z + q.w*q.w;
    }
    #pragma unroll
    for (int off = 32; off; off >>= 1){ s += __shfl_down(s, off); ss += __shfl_down(ss, off); }
    __shared__ float ls[4][2];
    if ((t & 63) == 0){ ls[t>>6][0] = s; ls[t>>6][1] = ss; }
    __syncthreads();
    if (t == 0){
        s  = ls[0][0] + ls[1][0] + ls[2][0] + ls[3][0];
        ss = ls[0][1] + ls[1][1] + ls[2][1] + ls[3][1];
        part[(bg*128 + blk)*2]     = s;
        part[(bg*128 + blk)*2 + 1] = ss;
    }
}

__global__ __launch_bounds__(128) void k_gn1_final(const float* __restrict__ part,
                                                   float* __restrict__ stat){
    const int bg = blockIdx.x, t = threadIdx.x;
    float s  = part[(bg*128 + t)*2];
    float ss = part[(bg*128 + t)*2 + 1];
    #pragma unroll
    for (int off = 32; off; off >>= 1){ s += __shfl_down(s, off); ss += __shfl_down(ss, off); }
    __shared__ float ls[2][2];
    if ((t & 63) == 0){ ls[t>>6][0] = s; ls[t>>6][1] = ss; }
    __syncthreads();
    if (t == 0){
        s  = ls[0][0] + ls[1][0];
        ss = ls[0][1] + ls[1][1];
        float m = s / (float)N_GN1;
        float v = ss / (float)N_GN1 - m*m;
        stat[bg*2]     = m;
        stat[bg*2 + 1] = 1.0f / sqrtf(v + 1e-5f);
    }
}

// ---------------- weight transpose + bf16 convert ----------------
// wbf[co][k*128 + c] = bf16(weight[co][c*7 + k])
__global__ __launch_bounds__(256) void k_wcvt(const float* __restrict__ wsrc,
                                              unsigned short* __restrict__ wbf){
    const int co = blockIdx.x;
    const int t = threadIdx.x;
    for (int r = t; r < 896; r += 256){
        int k = r >> 7, c = r & 127;
        wbf[co*896 + r] = f2b(wsrc[co*896 + c*7 + k]);
    }
}

// ---------------- fused MLP + residual ----------------
// grid (1019, 2), 256 thr.  64-pixel tile.  LDS: xn bf16 [128][64], h1 bf16 [256][64].
__global__ __launch_bounds__(256) void k_mlp(
    const float* __restrict__ x, const float* __restrict__ stat,
    const float* __restrict__ g1, const float* __restrict__ be1,
    const float* __restrict__ w1, const float* __restrict__ b1,
    const float* __restrict__ w2, const float* __restrict__ b2,
    float* __restrict__ skip)
{
    __shared__ unsigned short xns[128*64];
    __shared__ unsigned short h1s[256*64];
    const int t = threadIdx.x;
    const int b = blockIdx.y;
    const int pix0 = blockIdx.x * 64;
    int valid = HW - pix0; if (valid > 64) valid = 64;

    { // stage normalized input tile
        const int p = t & 63, cq = t >> 6;
        for (int c = cq; c < 128; c += 4){
            float v = 0.f;
            if (p < valid){
                float m = stat[(b*8 + (c >> 4))*2];
                float r = stat[(b*8 + (c >> 4))*2 + 1];
                v = (x[(size_t)(b*128 + c)*HW + pix0 + p] - m) * r * g1[c] + be1[c];
            }
            xns[c*64 + p] = f2b(v);
        }
    }
    __syncthreads();

    const int oq = t >> 4, pq = t & 15;

    // GEMM1: h1 = gelu(w1 @ xn + b1), 4 chunks of 64 output channels
    #pragma unroll 1
    for (int ch = 0; ch < 4; ++ch){
        const int ob = ch*64 + oq*4;
        float acc[4][4];
        #pragma unroll
        for (int i = 0; i < 4; ++i){
            float bv = b1[ob + i];
            #pragma unroll
            for (int j = 0; j < 4; ++j) acc[i][j] = bv;
        }
        const float* wr0 = w1 + (size_t)(ob+0)*128;
        const float* wr1 = w1 + (size_t)(ob+1)*128;
        const float* wr2 = w1 + (size_t)(ob+2)*128;
        const float* wr3 = w1 + (size_t)(ob+3)*128;
        #pragma unroll 4
        for (int c = 0; c < 128; ++c){
            uint2 q = *(const uint2*)(&xns[c*64 + pq*4]);
            float x0 = blo(q.x), x1 = bhi(q.x), x2 = blo(q.y), x3 = bhi(q.y);
            float w0v = wr0[c], w1v = wr1[c], w2v = wr2[c], w3v = wr3[c];
            acc[0][0] += w0v*x0; acc[0][1] += w0v*x1; acc[0][2] += w0v*x2; acc[0][3] += w0v*x3;
            acc[1][0] += w1v*x0; acc[1][1] += w1v*x1; acc[1][2] += w1v*x2; acc[1][3] += w1v*x3;
            acc[2][0] += w2v*x0; acc[2][1] += w2v*x1; acc[2][2] += w2v*x2; acc[2][3] += w2v*x3;
            acc[3][0] += w3v*x0; acc[3][1] += w3v*x1; acc[3][2] += w3v*x2; acc[3][3] += w3v*x3;
        }
        #pragma unroll
        for (int i = 0; i < 4; ++i){
            float g0 = gelu_f(acc[i][0]), g1v = gelu_f(acc[i][1]);
            float g2v = gelu_f(acc[i][2]), g3v = gelu_f(acc[i][3]);
            uint2 pk;
            pk.x = (unsigned)f2b(g0)  | ((unsigned)f2b(g1v) << 16);
            pk.y = (unsigned)f2b(g2v) | ((unsigned)f2b(g3v) << 16);
            *(uint2*)(&h1s[(ob+i)*64 + pq*4]) = pk;
        }
    }
    __syncthreads();

    // GEMM2: skip = w2 @ h1 + b2 + x, 2 chunks of 64 output channels
    #pragma unroll 1
    for (int ch = 0; ch < 2; ++ch){
        const int ob = ch*64 + oq*4;
        float acc[4][4];
        #pragma unroll
        for (int i = 0; i < 4; ++i){
            float bv = b2[ob + i];
            #pragma unroll
            for (int j = 0; j < 4; ++j) acc[i][j] = bv;
        }
        const float* wr0 = w2 + (size_t)(ob+0)*256;
        const float* wr1 = w2 + (size_t)(ob+1)*256;
        const float* wr2p = w2 + (size_t)(ob+2)*256;
        const float* wr3 = w2 + (size_t)(ob+3)*256;
        #pragma unroll 4
        for (int k = 0; k < 256; ++k){
            uint2 q = *(const uint2*)(&h1s[k*64 + pq*4]);
            float x0 = blo(q.x), x1 = bhi(q.x), x2 = blo(q.y), x3 = bhi(q.y);
            float w0v = wr0[k], w1v = wr1[k], w2v = wr2p[k], w3v = wr3[k];
            acc[0][0] += w0v*x0; acc[0][1] += w0v*x1; acc[0][2] += w0v*x2; acc[0][3] += w0v*x3;
            acc[1][0] += w1v*x0; acc[1][1] += w1v*x1; acc[1][2] += w1v*x2; acc[1][3] += w1v*x3;
            acc[2][0] += w2v*x0; acc[2][1] += w2v*x1; acc[2][2] += w2v*x2; acc[2][3] += w2v*x3;
            acc[3][0] += w3v*x0; acc[3][1] += w3v*x1; acc[3][2] += w3v*x2; acc[3][3] += w3v*x3;
        }
        const int p = pq*4;
        #pragma unroll
        for (int i = 0; i < 4; ++i){
            if (p + 3 < valid){
                const int cc = ob + i;
                size_t base = (size_t)(b*128 + cc)*HW + pix0 + p;
                float4 xv = *(const float4*)(x + base);
                float4 o;
                o.x = acc[i][0] + xv.x; o.y = acc[i][1] + xv.y;
                o.z = acc[i][2] + xv.z; o.w = acc[i][3] + xv.w;
                *(float4*)(skip + base) = o;
            }
        }
    }
}

// ---------------- DISCO conv (MFMA) + GN2 partials ----------------
// grid (2 wo-halves, 91 ho, 4 = b*2+coh), 256 thr (4 waves).
// Block computes out[co0:co0+128][wo0:wo0+90] for one (b,ho), K = 896 (= 7k x 128c).
__global__ __launch_bounds__(256, 2) void k_disco(
    const float* __restrict__ skip,
    const float* __restrict__ psi_v, const int* __restrict__ psi_hi, const int* __restrict__ psi_wi,
    const unsigned short* __restrict__ wbf, const float* __restrict__ bias,
    float* __restrict__ xdown, float* __restrict__ part)
{
    // y tile: [96 wo][row of 512B], element (k,c_local) at byte (k*64 + c*2) ^ ((wo&7)<<4)
    __shared__ unsigned short yT[96*256];   // 49152 B

    const int t   = threadIdx.x;
    const int woh = blockIdx.x;             // 0..1
    const int ho  = blockIdx.y;             // 0..90
    const int z   = blockIdx.z;             // b*2 + coh
    const int b   = z >> 1, coh = z & 1;
    const int co0 = coh * 128;
    const int wo0 = woh * 90;

    const int w  = t >> 6;                  // wave id
    const int l  = t & 63;
    const int wm = w >> 1, wn = w & 1;      // wave tile: rows co0+wm*64.. , cols wn*48..

    // y-build mapping
    const int wol = t & 31;                 // wo lane
    const int cq  = t >> 5;                 // 0..7 (c sub-block of 4)
    const unsigned sw = (unsigned)(wol & 7) << 4;

    const float* skipb = skip + (size_t)b * (128*HW);

    f32x4 acc[4][3];
    #pragma unroll
    for (int m = 0; m < 4; ++m)
        #pragma unroll
        for (int nf = 0; nf < 3; ++nf) acc[m][nf] = (f32x4)0.f;

    #pragma unroll 1
    for (int cc = 0; cc < 4; ++cc){
        __syncthreads();                    // previous-iter readers done before overwrite

        // ---- build y[k][c_local][wo] for channels cc*32 .. cc*32+32 ----
        const float* bp0 = skipb + (size_t)(cc*32 + cq*4 + 0)*HW;
        const float* bp1 = skipb + (size_t)(cc*32 + cq*4 + 1)*HW;
        const float* bp2 = skipb + (size_t)(cc*32 + cq*4 + 2)*HW;
        const float* bp3 = skipb + (size_t)(cc*32 + cq*4 + 3)*HW;

        float ya[3][4][7];
        #pragma unroll
        for (int wj = 0; wj < 3; ++wj)
            #pragma unroll
            for (int ci = 0; ci < 4; ++ci)
                #pragma unroll
                for (int k = 0; k < 7; ++k) ya[wj][ci][k] = 0.f;

        #pragma unroll 2
        for (int n = 0; n < NNZ; ++n){
            const int hi = psi_hi[ho*NNZ + n];
            const int wi = psi_wi[ho*NNZ + n];
            float ps[7];
            #pragma unroll
            for (int k = 0; k < 7; ++k) ps[k] = psi_v[(k*HOUT + ho)*NNZ + n];
            const int rowb = hi * WIN;
            #pragma unroll
            for (int wj = 0; wj < 3; ++wj){
                int wv = wi + 2*(wo0 + wol + 32*wj);
                wv = (wv >= 720) ? (wv - 720) : (wv >= 360 ? (wv - 360) : wv);
                const int off = rowb + wv;
                float g0 = bp0[off], g1 = bp1[off], g2 = bp2[off], g3 = bp3[off];
                #pragma unroll
                for (int k = 0; k < 7; ++k){
                    float pv = ps[k];
                    ya[wj][0][k] += pv*g0; ya[wj][1][k] += pv*g1;
                    ya[wj][2][k] += pv*g2; ya[wj][3][k] += pv*g3;
                }
            }
        }
        // write to swizzled LDS (pack c pairs into u32)
        #pragma unroll
        for (int wj = 0; wj < 3; ++wj){
            char* row = (char*)yT + (wol + 32*wj)*512;
            #pragma unroll
            for (int k = 0; k < 7; ++k){
                unsigned base = ((unsigned)(k*64 + cq*8)) ^ sw;
                unsigned p0 = (unsigned)f2b(ya[wj][0][k]) | ((unsigned)f2b(ya[wj][1][k]) << 16);
                unsigned p1 = (unsigned)f2b(ya[wj][2][k]) | ((unsigned)f2b(ya[wj][3][k]) << 16);
                *(unsigned*)(row + base)     = p0;
                *(unsigned*)(row + base + 4) = p1;
            }
        }
        __syncthreads();

        // ---- MFMA: 7 K-slices (k fixed, 32 c) ----
        const unsigned short* wrow = wbf + (size_t)(co0 + wm*64 + (l & 15))*896
                                         + cc*32 + ((l >> 4) << 3);
        #pragma unroll
        for (int k = 0; k < 7; ++k){
            bf16x8 af[4];
            #pragma unroll
            for (int m = 0; m < 4; ++m)
                af[m] = __builtin_bit_cast(bf16x8,
                          *(const uint4*)(wrow + (size_t)m*16*896 + k*128));
            bf16x8 bfv[3];
            #pragma unroll
            for (int nf = 0; nf < 3; ++nf){
                const int wo_l = wn*48 + nf*16 + (l & 15);
                unsigned off = (unsigned)(wo_l*512)
                             + (((unsigned)(k*64) + ((unsigned)(l >> 4) << 4))
                                ^ ((unsigned)(wo_l & 7) << 4));
                bfv[nf] = __builtin_bit_cast(bf16x8, *(const uint4*)((const char*)yT + off));
            }
            #pragma unroll
            for (int m = 0; m < 4; ++m)
                #pragma unroll
                for (int nf = 0; nf < 3; ++nf)
                    acc[m][nf] = __builtin_amdgcn_mfma_f32_16x16x32_bf16(af[m], bfv[nf], acc[m][nf], 0, 0, 0);
        }
    }

    // ---- epilogue: bias, store, GN2 partials ----
    float s[2] = {0.f, 0.f}, ss[2] = {0.f, 0.f};
    #pragma unroll
    for (int m = 0; m < 4; ++m){
        const int pair = m >> 1;
        const int cob = co0 + wm*64 + m*16 + ((l >> 4) << 2);
        float4 bv = *(const float4*)(bias + cob);
        #pragma unroll
        for (int nf = 0; nf < 3; ++nf){
            const int wo_t = wn*48 + nf*16 + (l & 15);
            if (wo_t < 90){
                #pragma unroll
                for (int r = 0; r < 4; ++r){
                    float v = acc[m][nf][r] + ((const float*)&bv)[r];
                    xdown[((size_t)(b*256 + cob + r)*HOUT + ho)*WOUT + wo0 + wo_t] = v;
                    s[pair] += v; ss[pair] += v*v;
                }
            }
        }
    }
    #pragma unroll
    for (int off = 32; off; off >>= 1){
        s[0] += __shfl_down(s[0], off); ss[0] += __shfl_down(ss[0], off);
        s[1] += __shfl_down(s[1], off); ss[1] += __shfl_down(ss[1], off);
    }
    if (l == 0){
        const int tid = (z*91 + ho)*2 + woh;
        part[(tid*8 + w*2 + 0)*2]     = s[0];
        part[(tid*8 + w*2 + 0)*2 + 1] = ss[0];
        part[(tid*8 + w*2 + 1)*2]     = s[1];
        part[(tid*8 + w*2 + 1)*2 + 1] = ss[1];
    }
}

// ---------------- GN2 finalize ----------------
// part layout: [tid = ((b*2+coh)*91+ho)*2+woh][slot = (wm*2+wn)*2+pair][{s,ss}]
// group g = coh*4 + wm*2 + pair
__global__ __launch_bounds__(256) void k_gn2_final(const float* __restrict__ part,
                                                   float* __restrict__ stat){
    const int bg = blockIdx.x, b = bg >> 3, g = bg & 7, t = threadIdx.x;
    const int coh = g >> 2, gl = g & 3, wm = gl >> 1, pair = gl & 1;
    float s = 0.f, ss = 0.f;
    for (int i = t; i < 364; i += 256){
        int ho = i >> 2, r = i & 3, woh = r >> 1, wn = r & 1;
        int tid = (((b*2 + coh)*91 + ho)*2 + woh);
        int slot = (wm*2 + wn)*2 + pair;
        s  += part[(tid*8 + slot)*2];
        ss += part[(tid*8 + slot)*2 + 1];
    }
    #pragma unroll
    for (int off = 32; off; off >>= 1){ s += __shfl_down(s, off); ss += __shfl_down(ss, off); }
    __shared__ float ls[4][2];
    if ((t & 63) == 0){ ls[t>>6][0] = s; ls[t>>6][1] = ss; }
    __syncthreads();
    if (t == 0){
        s  = ls[0][0] + ls[1][0] + ls[2][0] + ls[3][0];
        ss = ls[0][1] + ls[1][1] + ls[2][1] + ls[3][1];
        float m = s / (float)N_GN2;
        float v = ss / (float)N_GN2 - m*m;
        stat[bg*2]     = m;
        stat[bg*2 + 1] = 1.0f / sqrtf(v + 1e-5f);
    }
}

// ---------------- GN2 apply + gelu (in place) ----------------
__global__ __launch_bounds__(256) void k_gn2_apply(float* __restrict__ xd,
                                                   const float* __restrict__ stat,
                                                   const float* __restrict__ g2a,
                                                   const float* __restrict__ be2){
    const int gid = blockIdx.x*256 + threadIdx.x;
    const int stride = gridDim.x*256;
    for (int v = gid; v < 2096640; v += stride){
        float4 q = ((float4*)xd)[v];
        int i  = v << 2;
        int bc = i / 16380;                 // (b*256 + co); 16380 = 91*180 (mult of 4)
        int co = bc & 255, b = bc >> 8;
        float m  = stat[(b*8 + (co >> 5))*2];
        float r  = stat[(b*8 + (co >> 5))*2 + 1];
        float ga = g2a[co], be = be2[co];
        q.x = gelu_f((q.x - m)*r*ga + be);
        q.y = gelu_f((q.y - m)*r*ga + be);
        q.z = gelu_f((q.z - m)*r*ga + be);
        q.w = gelu_f((q.w - m)*r*ga + be);
        ((float4*)xd)[v] = q;
    }
}

extern "C" void kernel_launch(void* const* d_in, const int* in_sizes, int n_in,
                              void* d_out, int out_size, void* d_ws, size_t ws_size,
                              hipStream_t stream){
    const float* x      = (const float*)d_in[0];
    const float* psi_v  = (const float*)d_in[1];
    const int*   psi_hi = (const int*)d_in[2];
    const int*   psi_wi = (const int*)d_in[3];
    const float* weight = (const float*)d_in[4];
    const float* bias   = (const float*)d_in[5];
    const float* g1     = (const float*)d_in[6];
    const float* be1    = (const float*)d_in[7];
    const float* w1     = (const float*)d_in[8];
    const float* b1     = (const float*)d_in[9];
    const float* w2     = (const float*)d_in[10];
    const float* b2     = (const float*)d_in[11];
    const float* g2     = (const float*)d_in[12];
    const float* be2    = (const float*)d_in[13];

    float* skip  = (float*)d_out;
    float* xdown = skip + 16680960;          // 2*128*181*360

    float* ws       = (float*)d_ws;
    float* gn1_part = ws;                    // 4096 floats
    float* gn1_stat = ws + 4096;             // 32
    float* gn2_part = ws + 4128;             // 728*8*2 = 11648
    float* gn2_stat = ws + 4128 + 11648;     // 32
    unsigned short* wbf = (unsigned short*)(ws + 15808);  // 229376 ushort, 16B-aligned

    k_gn1_partial<<<dim3(128, 16), 256, 0, stream>>>(x, gn1_part);
    k_gn1_final  <<<16, 128, 0, stream>>>(gn1_part, gn1_stat);
    k_wcvt       <<<256, 256, 0, stream>>>(weight, wbf);
    k_mlp        <<<dim3(1019, 2), 256, 0, stream>>>(x, gn1_stat, g1, be1, w1, b1, w2, b2, skip);
    k_disco      <<<dim3(2, 91, 4), 256, 0, stream>>>(skip, psi_v, psi_hi, psi_wi,
                                                      wbf, bias, xdown, gn2_part);
    k_gn2_final  <<<16, 256, 0, stream>>>(gn2_part, gn2_stat);
    k_gn2_apply  <<<2048, 256, 0, stream>>>(xdown, gn2_stat, g2, be2);
}

// Round 3
// 279.318 us; speedup vs baseline: 3.0941x; 1.8098x over previous
//
#include <hip/hip_runtime.h>

// DiscoDownBlock: GN1 -> 1x1 MLP (expand/gelu/project) + residual -> DISCO S2 conv
//                 -> GN2 -> gelu.  Outputs: skip [2,128,181,360], x_down [2,256,91,180]
//
// Round 3: MLP moved to bf16 MFMA (16x16x32), same fragment recipe as disco.
//  - k_wcvt_mlp converts w1/w2 to bf16 (already K-major for A-fragments).
//  - k_mlp: 64-pixel tile, xn bf16 in XOR-swizzled LDS [p][c] -> GEMM1 (w1) ->
//    gelu -> h1 bf16 swizzled LDS [p][oc] -> GEMM2 (w2) -> +b2 + residual.

#define HW      65160      // 181*360
#define HIN     181
#define WIN     360
#define HOUT    91
#define WOUT    180
#define CIN     128
#define COUT    256
#define KB      7
#define NNZ     16
#define N_GN1   1042560    // 16*HW
#define N_GN2   524160     // 32*91*180

typedef float  f32x4  __attribute__((ext_vector_type(4)));
typedef __bf16 bf16x8 __attribute__((ext_vector_type(8)));

__device__ __forceinline__ unsigned short f2b(float v){
    unsigned u = __float_as_uint(v);
    u += 0x7fffu + ((u >> 16) & 1u);          // round-to-nearest-even
    return (unsigned short)(u >> 16);
}

// tanh-approx gelu (matches jax.nn.gelu approximate=True), overflow-safe
__device__ __forceinline__ float gelu_f(float v){
    float z  = 0.7978845608028654f * (v + 0.044715f * v * v * v);
    float az = fabsf(z);
    float e  = __expf(-2.0f * az);            // in (0,1], no overflow
    float th = (1.0f - e) / (1.0f + e);
    th = copysignf(th, z);
    return 0.5f * v * (1.0f + th);
}

// ---------------- GN1 stats ----------------
__global__ __launch_bounds__(256) void k_gn1_partial(const float* __restrict__ x,
                                                     float* __restrict__ part){
    const int bg = blockIdx.y, blk = blockIdx.x, t = threadIdx.x;
    const float4* p4 = (const float4*)(x + (size_t)bg * N_GN1);
    float s = 0.f, ss = 0.f;
    for (int v = blk*256 + t; v < N_GN1/4; v += 128*256){
        float4 q = p4[v];
        s  += q.x + q.y + q.z + q.w;
        ss += q.x*q.x + q.y*q.y + q.z*q.z + q.w*q.w;
    }
    #pragma unroll
    for (int off = 32; off; off >>= 1){ s += __shfl_down(s, off); ss += __shfl_down(ss, off); }
    __shared__ float ls[4][2];
    if ((t & 63) == 0){ ls[t>>6][0] = s; ls[t>>6][1] = ss; }
    __syncthreads();
    if (t == 0){
        s  = ls[0][0] + ls[1][0] + ls[2][0] + ls[3][0];
        ss = ls[0][1] + ls[1][1] + ls[2][1] + ls[3][1];
        part[(bg*128 + blk)*2]     = s;
        part[(bg*128 + blk)*2 + 1] = ss;
    }
}

__global__ __launch_bounds__(128) void k_gn1_final(const float* __restrict__ part,
                                                   float* __restrict__ stat){
    const int bg = blockIdx.x, t = threadIdx.x;
    float s  = part[(bg*128 + t)*2];
    float ss = part[(bg*128 + t)*2 + 1];
    #pragma unroll
    for (int off = 32; off; off >>= 1){ s += __shfl_down(s, off); ss += __shfl_down(ss, off); }
    __shared__ float ls[2][2];
    if ((t & 63) == 0){ ls[t>>6][0] = s; ls[t>>6][1] = ss; }
    __syncthreads();
    if (t == 0){
        s  = ls[0][0] + ls[1][0];
        ss = ls[0][1] + ls[1][1];
        float m = s / (float)N_GN1;
        float v = ss / (float)N_GN1 - m*m;
        stat[bg*2]     = m;
        stat[bg*2 + 1] = 1.0f / sqrtf(v + 1e-5f);
    }
}

// ---------------- weight converts ----------------
// wbf[co][k*128 + c] = bf16(weight[co][c*7 + k])
__global__ __launch_bounds__(256) void k_wcvt(const float* __restrict__ wsrc,
                                              unsigned short* __restrict__ wbf){
    const int co = blockIdx.x;
    const int t = threadIdx.x;
    for (int r = t; r < 896; r += 256){
        int k = r >> 7, c = r & 127;
        wbf[co*896 + r] = f2b(wsrc[co*896 + c*7 + k]);
    }
}

// w1 [256][128], w2 [128][256] -> bf16 (layouts already K-major)
__global__ __launch_bounds__(256) void k_wcvt_mlp(const float* __restrict__ w1,
                                                  const float* __restrict__ w2,
                                                  unsigned short* __restrict__ w1b,
                                                  unsigned short* __restrict__ w2b){
    const int i = blockIdx.x*256 + threadIdx.x;
    if (i < 32768){
        w1b[i] = f2b(w1[i]);
        w2b[i] = f2b(w2[i]);
    }
}

// ---------------- fused MLP + residual (MFMA) ----------------
// grid (1019, 2), 256 thr (4 waves). 64-pixel tile.
// LDS: xn bf16 [64 p][128 c] swizzled (16 KB), h1 bf16 [64 p][256 oc] swizzled (32 KB).
__global__ __launch_bounds__(256, 2) void k_mlp(
    const float* __restrict__ x, const float* __restrict__ stat,
    const float* __restrict__ g1, const float* __restrict__ be1,
    const unsigned short* __restrict__ w1b, const float* __restrict__ b1,
    const unsigned short* __restrict__ w2b, const float* __restrict__ b2,
    float* __restrict__ skip)
{
    __shared__ unsigned short xns[64*128];
    __shared__ unsigned short h1s[64*256];

    const int t = threadIdx.x;
    const int b = blockIdx.y;
    const int pix0 = blockIdx.x * 64;
    const int valid = min(64, HW - pix0);

    const int w  = t >> 6, l = t & 63;
    const int lr = l & 15, lk = l >> 4;

    // ---- stage normalized xn tile: thread (p=l, c-chunk=w*32..+32) ----
    {
        const int p = l;
        const unsigned sw = ((unsigned)(p & 7)) << 4;
        #pragma unroll
        for (int i = 0; i < 4; ++i){
            const int c0 = w*32 + i*8;
            unsigned short tmp[8];
            #pragma unroll
            for (int j = 0; j < 8; ++j){
                const int c = c0 + j;
                float v = 0.f;
                if (p < valid){
                    float m = stat[(b*8 + (c >> 4))*2];
                    float r = stat[(b*8 + (c >> 4))*2 + 1];
                    v = (x[(size_t)(b*128 + c)*HW + pix0 + p] - m) * r * g1[c] + be1[c];
                }
                tmp[j] = f2b(v);
            }
            *(uint4*)((char*)xns + p*256 + (((unsigned)(c0*2)) ^ sw)) = *(const uint4*)tmp;
        }
    }
    __syncthreads();

    // ---- GEMM1: h1[oc][p] = gelu(w1 @ xn + b1); wave owns oc block w*64..+64 ----
    {
        f32x4 acc[4][4];
        #pragma unroll
        for (int m = 0; m < 4; ++m){
            float4 bv = *(const float4*)(b1 + w*64 + m*16 + lk*4);
            #pragma unroll
            for (int nf = 0; nf < 4; ++nf) acc[m][nf] = __builtin_bit_cast(f32x4, bv);
        }
        const unsigned short* wr = w1b + (size_t)(w*64 + lr)*128 + lk*8;
        #pragma unroll
        for (int ks = 0; ks < 4; ++ks){
            bf16x8 af[4];
            #pragma unroll
            for (int m = 0; m < 4; ++m)
                af[m] = __builtin_bit_cast(bf16x8, *(const uint4*)(wr + m*16*128 + ks*32));
            bf16x8 bfv[4];
            #pragma unroll
            for (int nf = 0; nf < 4; ++nf){
                const int p = nf*16 + lr;
                unsigned off = (unsigned)(p*256)
                             + (((unsigned)(ks*64 + lk*16)) ^ (((unsigned)(p & 7)) << 4));
                bfv[nf] = __builtin_bit_cast(bf16x8, *(const uint4*)((const char*)xns + off));
            }
            #pragma unroll
            for (int m = 0; m < 4; ++m)
                #pragma unroll
                for (int nf = 0; nf < 4; ++nf)
                    acc[m][nf] = __builtin_amdgcn_mfma_f32_16x16x32_bf16(af[m], bfv[nf], acc[m][nf], 0, 0, 0);
        }
        // gelu + pack to h1 LDS
        #pragma unroll
        for (int m = 0; m < 4; ++m){
            const int oc0 = w*64 + m*16 + lk*4;
            #pragma unroll
            for (int nf = 0; nf < 4; ++nf){
                const int p = nf*16 + lr;
                unsigned q0 = (unsigned)f2b(gelu_f(acc[m][nf][0]))
                            | ((unsigned)f2b(gelu_f(acc[m][nf][1])) << 16);
                unsigned q1 = (unsigned)f2b(gelu_f(acc[m][nf][2]))
                            | ((unsigned)f2b(gelu_f(acc[m][nf][3])) << 16);
                uint2 pk; pk.x = q0; pk.y = q1;
                unsigned off = (unsigned)(p*512)
                             + (((unsigned)(oc0*2)) ^ (((unsigned)(p & 7)) << 4));
                *(uint2*)((char*)h1s + off) = pk;
            }
        }
    }
    __syncthreads();

    // ---- GEMM2: skip[c][p] = w2 @ h1 + b2 + x; wave owns c block w*32..+32 ----
    {
        f32x4 acc[2][4];
        #pragma unroll
        for (int m = 0; m < 2; ++m){
            float4 bv = *(const float4*)(b2 + w*32 + m*16 + lk*4);
            #pragma unroll
            for (int nf = 0; nf < 4; ++nf) acc[m][nf] = __builtin_bit_cast(f32x4, bv);
        }
        const unsigned short* wr = w2b + (size_t)(w*32 + lr)*256 + lk*8;
        #pragma unroll
        for (int ks = 0; ks < 8; ++ks){
            bf16x8 af[2];
            #pragma unroll
            for (int m = 0; m < 2; ++m)
                af[m] = __builtin_bit_cast(bf16x8, *(const uint4*)(wr + m*16*256 + ks*32));
            bf16x8 bfv[4];
            #pragma unroll
            for (int nf = 0; nf < 4; ++nf){
                const int p = nf*16 + lr;
                unsigned off = (unsigned)(p*512)
                             + (((unsigned)(ks*64 + lk*16)) ^ (((unsigned)(p & 7)) << 4));
                bfv[nf] = __builtin_bit_cast(bf16x8, *(const uint4*)((const char*)h1s + off));
            }
            #pragma unroll
            for (int m = 0; m < 2; ++m)
                #pragma unroll
                for (int nf = 0; nf < 4; ++nf)
                    acc[m][nf] = __builtin_amdgcn_mfma_f32_16x16x32_bf16(af[m], bfv[nf], acc[m][nf], 0, 0, 0);
        }
        // epilogue: + residual, store
        #pragma unroll
        for (int m = 0; m < 2; ++m){
            const int c0 = w*32 + m*16 + lk*4;
            #pragma unroll
            for (int nf = 0; nf < 4; ++nf){
                const int p = nf*16 + lr;
                if (p < valid){
                    #pragma unroll
                    for (int r = 0; r < 4; ++r){
                        size_t base = (size_t)(b*128 + c0 + r)*HW + pix0 + p;
                        skip[base] = acc[m][nf][r] + x[base];
                    }
                }
            }
        }
    }
}

// ---------------- DISCO conv (MFMA) + GN2 partials ----------------
// grid (2 wo-halves, 91 ho, 4 = b*2+coh), 256 thr (4 waves).
__global__ __launch_bounds__(256, 2) void k_disco(
    const float* __restrict__ skip,
    const float* __restrict__ psi_v, const int* __restrict__ psi_hi, const int* __restrict__ psi_wi,
    const unsigned short* __restrict__ wbf, const float* __restrict__ bias,
    float* __restrict__ xdown, float* __restrict__ part)
{
    __shared__ unsigned short yT[96*256];   // rows 512B, (k*64+c*2) ^ ((wo&7)<<4)

    const int t   = threadIdx.x;
    const int woh = blockIdx.x;
    const int ho  = blockIdx.y;
    const int z   = blockIdx.z;
    const int b   = z >> 1, coh = z & 1;
    const int co0 = coh * 128;
    const int wo0 = woh * 90;

    const int w  = t >> 6;
    const int l  = t & 63;
    const int wm = w >> 1, wn = w & 1;

    const int wol = t & 31;
    const int cq  = t >> 5;
    const unsigned sw = (unsigned)(wol & 7) << 4;

    const float* skipb = skip + (size_t)b * (128*HW);

    f32x4 acc[4][3];
    #pragma unroll
    for (int m = 0; m < 4; ++m)
        #pragma unroll
        for (int nf = 0; nf < 3; ++nf) acc[m][nf] = (f32x4)0.f;

    #pragma unroll 1
    for (int cc = 0; cc < 4; ++cc){
        __syncthreads();

        const float* bp0 = skipb + (size_t)(cc*32 + cq*4 + 0)*HW;
        const float* bp1 = skipb + (size_t)(cc*32 + cq*4 + 1)*HW;
        const float* bp2 = skipb + (size_t)(cc*32 + cq*4 + 2)*HW;
        const float* bp3 = skipb + (size_t)(cc*32 + cq*4 + 3)*HW;

        float ya[3][4][7];
        #pragma unroll
        for (int wj = 0; wj < 3; ++wj)
            #pragma unroll
            for (int ci = 0; ci < 4; ++ci)
                #pragma unroll
                for (int k = 0; k < 7; ++k) ya[wj][ci][k] = 0.f;

        #pragma unroll 2
        for (int n = 0; n < NNZ; ++n){
            const int hi = psi_hi[ho*NNZ + n];
            const int wi = psi_wi[ho*NNZ + n];
            float ps[7];
            #pragma unroll
            for (int k = 0; k < 7; ++k) ps[k] = psi_v[(k*HOUT + ho)*NNZ + n];
            const int rowb = hi * WIN;
            #pragma unroll
            for (int wj = 0; wj < 3; ++wj){
                int wv = wi + 2*(wo0 + wol + 32*wj);
                wv = (wv >= 720) ? (wv - 720) : (wv >= 360 ? (wv - 360) : wv);
                const int off = rowb + wv;
                float g0 = bp0[off], g1 = bp1[off], g2 = bp2[off], g3 = bp3[off];
                #pragma unroll
                for (int k = 0; k < 7; ++k){
                    float pv = ps[k];
                    ya[wj][0][k] += pv*g0; ya[wj][1][k] += pv*g1;
                    ya[wj][2][k] += pv*g2; ya[wj][3][k] += pv*g3;
                }
            }
        }
        #pragma unroll
        for (int wj = 0; wj < 3; ++wj){
            char* row = (char*)yT + (wol + 32*wj)*512;
            #pragma unroll
            for (int k = 0; k < 7; ++k){
                unsigned base = ((unsigned)(k*64 + cq*8)) ^ sw;
                unsigned p0 = (unsigned)f2b(ya[wj][0][k]) | ((unsigned)f2b(ya[wj][1][k]) << 16);
                unsigned p1 = (unsigned)f2b(ya[wj][2][k]) | ((unsigned)f2b(ya[wj][3][k]) << 16);
                *(unsigned*)(row + base)     = p0;
                *(unsigned*)(row + base + 4) = p1;
            }
        }
        __syncthreads();

        const unsigned short* wrow = wbf + (size_t)(co0 + wm*64 + (l & 15))*896
                                         + cc*32 + ((l >> 4) << 3);
        #pragma unroll
        for (int k = 0; k < 7; ++k){
            bf16x8 af[4];
            #pragma unroll
            for (int m = 0; m < 4; ++m)
                af[m] = __builtin_bit_cast(bf16x8,
                          *(const uint4*)(wrow + (size_t)m*16*896 + k*128));
            bf16x8 bfv[3];
            #pragma unroll
            for (int nf = 0; nf < 3; ++nf){
                const int wo_l = wn*48 + nf*16 + (l & 15);
                unsigned off = (unsigned)(wo_l*512)
                             + (((unsigned)(k*64) + ((unsigned)(l >> 4) << 4))
                                ^ ((unsigned)(wo_l & 7) << 4));
                bfv[nf] = __builtin_bit_cast(bf16x8, *(const uint4*)((const char*)yT + off));
            }
            #pragma unroll
            for (int m = 0; m < 4; ++m)
                #pragma unroll
                for (int nf = 0; nf < 3; ++nf)
                    acc[m][nf] = __builtin_amdgcn_mfma_f32_16x16x32_bf16(af[m], bfv[nf], acc[m][nf], 0, 0, 0);
        }
    }

    float s[2] = {0.f, 0.f}, ss[2] = {0.f, 0.f};
    #pragma unroll
    for (int m = 0; m < 4; ++m){
        const int pair = m >> 1;
        const int cob = co0 + wm*64 + m*16 + ((l >> 4) << 2);
        float4 bv = *(const float4*)(bias + cob);
        #pragma unroll
        for (int nf = 0; nf < 3; ++nf){
            const int wo_t = wn*48 + nf*16 + (l & 15);
            if (wo_t < 90){
                #pragma unroll
                for (int r = 0; r < 4; ++r){
                    float v = acc[m][nf][r] + ((const float*)&bv)[r];
                    xdown[((size_t)(b*256 + cob + r)*HOUT + ho)*WOUT + wo0 + wo_t] = v;
                    s[pair] += v; ss[pair] += v*v;
                }
            }
        }
    }
    #pragma unroll
    for (int off = 32; off; off >>= 1){
        s[0] += __shfl_down(s[0], off); ss[0] += __shfl_down(ss[0], off);
        s[1] += __shfl_down(s[1], off); ss[1] += __shfl_down(ss[1], off);
    }
    if (l == 0){
        const int tid = (z*91 + ho)*2 + woh;
        part[(tid*8 + w*2 + 0)*2]     = s[0];
        part[(tid*8 + w*2 + 0)*2 + 1] = ss[0];
        part[(tid*8 + w*2 + 1)*2]     = s[1];
        part[(tid*8 + w*2 + 1)*2 + 1] = ss[1];
    }
}

// ---------------- GN2 finalize ----------------
__global__ __launch_bounds__(256) void k_gn2_final(const float* __restrict__ part,
                                                   float* __restrict__ stat){
    const int bg = blockIdx.x, b = bg >> 3, g = bg & 7, t = threadIdx.x;
    const int coh = g >> 2, gl = g & 3, wm = gl >> 1, pair = gl & 1;
    float s = 0.f, ss = 0.f;
    for (int i = t; i < 364; i += 256){
        int ho = i >> 2, r = i & 3, woh = r >> 1, wn = r & 1;
        int tid = (((b*2 + coh)*91 + ho)*2 + woh);
        int slot = (wm*2 + wn)*2 + pair;
        s  += part[(tid*8 + slot)*2];
        ss += part[(tid*8 + slot)*2 + 1];
    }
    #pragma unroll
    for (int off = 32; off; off >>= 1){ s += __shfl_down(s, off); ss += __shfl_down(ss, off); }
    __shared__ float ls[4][2];
    if ((t & 63) == 0){ ls[t>>6][0] = s; ls[t>>6][1] = ss; }
    __syncthreads();
    if (t == 0){
        s  = ls[0][0] + ls[1][0] + ls[2][0] + ls[3][0];
        ss = ls[0][1] + ls[1][1] + ls[2][1] + ls[3][1];
        float m = s / (float)N_GN2;
        float v = ss / (float)N_GN2 - m*m;
        stat[bg*2]     = m;
        stat[bg*2 + 1] = 1.0f / sqrtf(v + 1e-5f);
    }
}

// ---------------- GN2 apply + gelu (in place) ----------------
__global__ __launch_bounds__(256) void k_gn2_apply(float* __restrict__ xd,
                                                   const float* __restrict__ stat,
                                                   const float* __restrict__ g2a,
                                                   const float* __restrict__ be2){
    const int gid = blockIdx.x*256 + threadIdx.x;
    const int stride = gridDim.x*256;
    for (int v = gid; v < 2096640; v += stride){
        float4 q = ((float4*)xd)[v];
        int i  = v << 2;
        int bc = i / 16380;                 // (b*256 + co); 16380 = 91*180 (mult of 4)
        int co = bc & 255, b = bc >> 8;
        float m  = stat[(b*8 + (co >> 5))*2];
        float r  = stat[(b*8 + (co >> 5))*2 + 1];
        float ga = g2a[co], be = be2[co];
        q.x = gelu_f((q.x - m)*r*ga + be);
        q.y = gelu_f((q.y - m)*r*ga + be);
        q.z = gelu_f((q.z - m)*r*ga + be);
        q.w = gelu_f((q.w - m)*r*ga + be);
        ((float4*)xd)[v] = q;
    }
}

extern "C" void kernel_launch(void* const* d_in, const int* in_sizes, int n_in,
                              void* d_out, int out_size, void* d_ws, size_t ws_size,
                              hipStream_t stream){
    const float* x      = (const float*)d_in[0];
    const float* psi_v  = (const float*)d_in[1];
    const int*   psi_hi = (const int*)d_in[2];
    const int*   psi_wi = (const int*)d_in[3];
    const float* weight = (const float*)d_in[4];
    const float* bias   = (const float*)d_in[5];
    const float* g1     = (const float*)d_in[6];
    const float* be1    = (const float*)d_in[7];
    const float* w1     = (const float*)d_in[8];
    const float* b1     = (const float*)d_in[9];
    const float* w2     = (const float*)d_in[10];
    const float* b2     = (const float*)d_in[11];
    const float* g2     = (const float*)d_in[12];
    const float* be2    = (const float*)d_in[13];

    float* skip  = (float*)d_out;
    float* xdown = skip + 16680960;          // 2*128*181*360

    float* ws       = (float*)d_ws;
    float* gn1_part = ws;                    // 4096 floats
    float* gn1_stat = ws + 4096;             // 32
    float* gn2_part = ws + 4128;             // 11648
    float* gn2_stat = ws + 4128 + 11648;     // 32
    unsigned short* wbf = (unsigned short*)(ws + 15808);   // 229376 ushort
    unsigned short* w1b = (unsigned short*)(ws + 130496);  // 32768 ushort
    unsigned short* w2b = (unsigned short*)(ws + 146880);  // 32768 ushort

    k_gn1_partial<<<dim3(128, 16), 256, 0, stream>>>(x, gn1_part);
    k_gn1_final  <<<16, 128, 0, stream>>>(gn1_part, gn1_stat);
    k_wcvt       <<<256, 256, 0, stream>>>(weight, wbf);
    k_wcvt_mlp   <<<128, 256, 0, stream>>>(w1, w2, w1b, w2b);
    k_mlp        <<<dim3(1019, 2), 256, 0, stream>>>(x, gn1_stat, g1, be1, w1b, b1, w2b, b2, skip);
    k_disco      <<<dim3(2, 91, 4), 256, 0, stream>>>(skip, psi_v, psi_hi, psi_wi,
                                                      wbf, bias, xdown, gn2_part);
    k_gn2_final  <<<16, 256, 0, stream>>>(gn2_part, gn2_stat);
    k_gn2_apply  <<<2048, 256, 0, stream>>>(xdown, gn2_stat, g2, be2);
}

// Round 4
// 226.842 us; speedup vs baseline: 3.8099x; 1.2313x over previous
//
#include <hip/hip_runtime.h>

// DiscoDownBlock: GN1 -> 1x1 MLP (expand/gelu/project) + residual -> DISCO S2 conv
//                 -> GN2 -> gelu.  Outputs: skip [2,128,181,360], x_down [2,256,91,180]
//
// Round 4: split DISCO into gather (k_ybuild) + pure no-LDS MFMA GEMM (k_dgemm).
//  - k_mlp also writes skip_bf16 [b][hw][c] (transposed) for line-perfect gathers.
//  - k_ybuild: Y_t[n][ck] bf16 in d_ws; each element computed once (no coh dup).
//  - k_dgemm: D[n][co] = Y_t @ W^T; both MFMA fragments are contiguous 16B global
//    loads (no LDS, no barriers); fused bias + GN2 partials; XCD swizzle.
//  - Fallback to round-3 fused k_disco if ws_size < ~93 MB.

#define HW      65160      // 181*360
#define HIN     181
#define WIN     360
#define HOUT    91
#define WOUT    180
#define CIN     128
#define COUT    256
#define KB      7
#define NNZ     16
#define N_GN1   1042560    // 16*HW
#define N_GN2   524160     // 32*91*180
#define NPB     16380      // 91*180 (per-batch n)

typedef float  f32x4  __attribute__((ext_vector_type(4)));
typedef __bf16 bf16x8 __attribute__((ext_vector_type(8)));

__device__ __forceinline__ unsigned short f2b(float v){
    unsigned u = __float_as_uint(v);
    u += 0x7fffu + ((u >> 16) & 1u);          // round-to-nearest-even
    return (unsigned short)(u >> 16);
}
__device__ __forceinline__ float blo(unsigned u){ return __uint_as_float(u << 16); }
__device__ __forceinline__ float bhi(unsigned u){ return __uint_as_float(u & 0xffff0000u); }

// tanh-approx gelu (matches jax.nn.gelu approximate=True), overflow-safe
__device__ __forceinline__ float gelu_f(float v){
    float z  = 0.7978845608028654f * (v + 0.044715f * v * v * v);
    float az = fabsf(z);
    float e  = __expf(-2.0f * az);
    float th = (1.0f - e) / (1.0f + e);
    th = copysignf(th, z);
    return 0.5f * v * (1.0f + th);
}

// ---------------- GN1 stats ----------------
__global__ __launch_bounds__(256) void k_gn1_partial(const float* __restrict__ x,
                                                     float* __restrict__ part){
    const int bg = blockIdx.y, blk = blockIdx.x, t = threadIdx.x;
    const float4* p4 = (const float4*)(x + (size_t)bg * N_GN1);
    float s = 0.f, ss = 0.f;
    for (int v = blk*256 + t; v < N_GN1/4; v += 128*256){
        float4 q = p4[v];
        s  += q.x + q.y + q.z + q.w;
        ss += q.x*q.x + q.y*q.y + q.z*q.z + q.w*q.w;
    }
    #pragma unroll
    for (int off = 32; off; off >>= 1){ s += __shfl_down(s, off); ss += __shfl_down(ss, off); }
    __shared__ float ls[4][2];
    if ((t & 63) == 0){ ls[t>>6][0] = s; ls[t>>6][1] = ss; }
    __syncthreads();
    if (t == 0){
        s  = ls[0][0] + ls[1][0] + ls[2][0] + ls[3][0];
        ss = ls[0][1] + ls[1][1] + ls[2][1] + ls[3][1];
        part[(bg*128 + blk)*2]     = s;
        part[(bg*128 + blk)*2 + 1] = ss;
    }
}

__global__ __launch_bounds__(128) void k_gn1_final(const float* __restrict__ part,
                                                   float* __restrict__ stat){
    const int bg = blockIdx.x, t = threadIdx.x;
    float s  = part[(bg*128 + t)*2];
    float ss = part[(bg*128 + t)*2 + 1];
    #pragma unroll
    for (int off = 32; off; off >>= 1){ s += __shfl_down(s, off); ss += __shfl_down(ss, off); }
    __shared__ float ls[2][2];
    if ((t & 63) == 0){ ls[t>>6][0] = s; ls[t>>6][1] = ss; }
    __syncthreads();
    if (t == 0){
        s  = ls[0][0] + ls[1][0];
        ss = ls[0][1] + ls[1][1];
        float m = s / (float)N_GN1;
        float v = ss / (float)N_GN1 - m*m;
        stat[bg*2]     = m;
        stat[bg*2 + 1] = 1.0f / sqrtf(v + 1e-5f);
    }
}

// ---------------- weight converts ----------------
// wbf[co][k*128 + c] = bf16(weight[co][c*7 + k])   (K-major rows, 1792 B)
__global__ __launch_bounds__(256) void k_wcvt(const float* __restrict__ wsrc,
                                              unsigned short* __restrict__ wbf){
    const int co = blockIdx.x;
    const int t = threadIdx.x;
    for (int r = t; r < 896; r += 256){
        int k = r >> 7, c = r & 127;
        wbf[co*896 + r] = f2b(wsrc[co*896 + c*7 + k]);
    }
}

__global__ __launch_bounds__(256) void k_wcvt_mlp(const float* __restrict__ w1,
                                                  const float* __restrict__ w2,
                                                  unsigned short* __restrict__ w1b,
                                                  unsigned short* __restrict__ w2b){
    const int i = blockIdx.x*256 + threadIdx.x;
    if (i < 32768){
        w1b[i] = f2b(w1[i]);
        w2b[i] = f2b(w2[i]);
    }
}

// ---------------- fused MLP + residual (MFMA) ----------------
// grid (1019, 2), 256 thr (4 waves). 64-pixel tile.
__global__ __launch_bounds__(256, 2) void k_mlp(
    const float* __restrict__ x, const float* __restrict__ stat,
    const float* __restrict__ g1, const float* __restrict__ be1,
    const unsigned short* __restrict__ w1b, const float* __restrict__ b1,
    const unsigned short* __restrict__ w2b, const float* __restrict__ b2,
    float* __restrict__ skip, unsigned short* __restrict__ sbf)
{
    __shared__ unsigned short xns[64*128];
    __shared__ unsigned short h1s[64*256];

    const int t = threadIdx.x;
    const int b = blockIdx.y;
    const int pix0 = blockIdx.x * 64;
    const int valid = min(64, HW - pix0);

    const int w  = t >> 6, l = t & 63;
    const int lr = l & 15, lk = l >> 4;

    { // stage normalized xn tile
        const int p = l;
        const unsigned sw = ((unsigned)(p & 7)) << 4;
        #pragma unroll
        for (int i = 0; i < 4; ++i){
            const int c0 = w*32 + i*8;
            unsigned short tmp[8];
            #pragma unroll
            for (int j = 0; j < 8; ++j){
                const int c = c0 + j;
                float v = 0.f;
                if (p < valid){
                    float m = stat[(b*8 + (c >> 4))*2];
                    float r = stat[(b*8 + (c >> 4))*2 + 1];
                    v = (x[(size_t)(b*128 + c)*HW + pix0 + p] - m) * r * g1[c] + be1[c];
                }
                tmp[j] = f2b(v);
            }
            *(uint4*)((char*)xns + p*256 + (((unsigned)(c0*2)) ^ sw)) = *(const uint4*)tmp;
        }
    }
    __syncthreads();

    // GEMM1
    {
        f32x4 acc[4][4];
        #pragma unroll
        for (int m = 0; m < 4; ++m){
            float4 bv = *(const float4*)(b1 + w*64 + m*16 + lk*4);
            #pragma unroll
            for (int nf = 0; nf < 4; ++nf) acc[m][nf] = __builtin_bit_cast(f32x4, bv);
        }
        const unsigned short* wr = w1b + (size_t)(w*64 + lr)*128 + lk*8;
        #pragma unroll
        for (int ks = 0; ks < 4; ++ks){
            bf16x8 af[4];
            #pragma unroll
            for (int m = 0; m < 4; ++m)
                af[m] = __builtin_bit_cast(bf16x8, *(const uint4*)(wr + m*16*128 + ks*32));
            bf16x8 bfv[4];
            #pragma unroll
            for (int nf = 0; nf < 4; ++nf){
                const int p = nf*16 + lr;
                unsigned off = (unsigned)(p*256)
                             + (((unsigned)(ks*64 + lk*16)) ^ (((unsigned)(p & 7)) << 4));
                bfv[nf] = __builtin_bit_cast(bf16x8, *(const uint4*)((const char*)xns + off));
            }
            #pragma unroll
            for (int m = 0; m < 4; ++m)
                #pragma unroll
                for (int nf = 0; nf < 4; ++nf)
                    acc[m][nf] = __builtin_amdgcn_mfma_f32_16x16x32_bf16(af[m], bfv[nf], acc[m][nf], 0, 0, 0);
        }
        #pragma unroll
        for (int m = 0; m < 4; ++m){
            const int oc0 = w*64 + m*16 + lk*4;
            #pragma unroll
            for (int nf = 0; nf < 4; ++nf){
                const int p = nf*16 + lr;
                unsigned q0 = (unsigned)f2b(gelu_f(acc[m][nf][0]))
                            | ((unsigned)f2b(gelu_f(acc[m][nf][1])) << 16);
                unsigned q1 = (unsigned)f2b(gelu_f(acc[m][nf][2]))
                            | ((unsigned)f2b(gelu_f(acc[m][nf][3])) << 16);
                uint2 pk; pk.x = q0; pk.y = q1;
                unsigned off = (unsigned)(p*512)
                             + (((unsigned)(oc0*2)) ^ (((unsigned)(p & 7)) << 4));
                *(uint2*)((char*)h1s + off) = pk;
            }
        }
    }
    __syncthreads();

    // GEMM2 + residual (+ bf16 transposed copy for the gather stage)
    {
        f32x4 acc[2][4];
        #pragma unroll
        for (int m = 0; m < 2; ++m){
            float4 bv = *(const float4*)(b2 + w*32 + m*16 + lk*4);
            #pragma unroll
            for (int nf = 0; nf < 4; ++nf) acc[m][nf] = __builtin_bit_cast(f32x4, bv);
        }
        const unsigned short* wr = w2b + (size_t)(w*32 + lr)*256 + lk*8;
        #pragma unroll
        for (int ks = 0; ks < 8; ++ks){
            bf16x8 af[2];
            #pragma unroll
            for (int m = 0; m < 2; ++m)
                af[m] = __builtin_bit_cast(bf16x8, *(const uint4*)(wr + m*16*256 + ks*32));
            bf16x8 bfv[4];
            #pragma unroll
            for (int nf = 0; nf < 4; ++nf){
                const int p = nf*16 + lr;
                unsigned off = (unsigned)(p*512)
                             + (((unsigned)(ks*64 + lk*16)) ^ (((unsigned)(p & 7)) << 4));
                bfv[nf] = __builtin_bit_cast(bf16x8, *(const uint4*)((const char*)h1s + off));
            }
            #pragma unroll
            for (int m = 0; m < 2; ++m)
                #pragma unroll
                for (int nf = 0; nf < 4; ++nf)
                    acc[m][nf] = __builtin_amdgcn_mfma_f32_16x16x32_bf16(af[m], bfv[nf], acc[m][nf], 0, 0, 0);
        }
        #pragma unroll
        for (int m = 0; m < 2; ++m){
            const int c0 = w*32 + m*16 + lk*4;
            #pragma unroll
            for (int nf = 0; nf < 4; ++nf){
                const int p = nf*16 + lr;
                if (p < valid){
                    float o[4];
                    size_t base = (size_t)(b*128 + c0)*HW + pix0 + p;
                    #pragma unroll
                    for (int r = 0; r < 4; ++r){
                        float vv = acc[m][nf][r] + x[base + (size_t)r*HW];
                        skip[base + (size_t)r*HW] = vv;
                        o[r] = vv;
                    }
                    if (sbf){
                        uint2 pk;
                        pk.x = (unsigned)f2b(o[0]) | ((unsigned)f2b(o[1]) << 16);
                        pk.y = (unsigned)f2b(o[2]) | ((unsigned)f2b(o[3]) << 16);
                        *(uint2*)(sbf + ((size_t)b*HW + pix0 + p)*128 + c0) = pk;
                    }
                }
            }
        }
    }
}

// ---------------- Y build: gather + psi reduce -> Y_t[n][ck] bf16 ----------------
// grid (6 wo-tiles of 32, 91 ho, 2 b), 256 thr = 32 wol x 8 cq. No c duplication.
__global__ __launch_bounds__(256) void k_ybuild(
    const unsigned short* __restrict__ sbf,
    const float* __restrict__ psi_v, const int* __restrict__ psi_hi, const int* __restrict__ psi_wi,
    unsigned short* __restrict__ Yt)
{
    __shared__ int   offh[16];
    __shared__ int   wis[16];
    __shared__ float psis[112];

    const int t   = threadIdx.x;
    const int wot = blockIdx.x, ho = blockIdx.y, b = blockIdx.z;

    if (t < 112) psis[t] = psi_v[((t >> 4)*HOUT + ho)*NNZ + (t & 15)];
    if (t < 16){ offh[t] = psi_hi[ho*NNZ + t] * WIN; wis[t] = psi_wi[ho*NNZ + t]; }
    __syncthreads();

    const int wol = t >> 3, cq = t & 7;
    const int wo  = wot*32 + wol;
    const bool valid = (wo < WOUT);
    const int wo_c = valid ? wo : (WOUT - 1);

    int offs[16];
    #pragma unroll
    for (int n = 0; n < 16; ++n){
        int wv = wis[n] + 2*wo_c;               // < 718
        wv = (wv >= WIN) ? (wv - WIN) : wv;
        offs[n] = offh[n] + wv;
    }

    const unsigned short* sb = sbf + (size_t)b * HW * 128;
    unsigned short* yrow = Yt + (size_t)(b*NPB + ho*WOUT + wo_c) * 896;

    #pragma unroll 1
    for (int cc = 0; cc < 4; ++cc){
        const int c0 = cc*32 + cq*4;
        float ya[4][7];
        #pragma unroll
        for (int ci = 0; ci < 4; ++ci)
            #pragma unroll
            for (int k = 0; k < 7; ++k) ya[ci][k] = 0.f;

        #pragma unroll 2
        for (int n = 0; n < 16; ++n){
            uint2 q = *(const uint2*)(sb + (size_t)offs[n]*128 + c0);
            float g0 = blo(q.x), g1 = bhi(q.x), g2 = blo(q.y), g3 = bhi(q.y);
            #pragma unroll
            for (int k = 0; k < 7; ++k){
                float pv = psis[k*16 + n];
                ya[0][k] += pv*g0; ya[1][k] += pv*g1;
                ya[2][k] += pv*g2; ya[3][k] += pv*g3;
            }
        }
        if (valid){
            #pragma unroll
            for (int k = 0; k < 7; ++k){
                uint2 pk;
                pk.x = (unsigned)f2b(ya[0][k]) | ((unsigned)f2b(ya[1][k]) << 16);
                pk.y = (unsigned)f2b(ya[2][k]) | ((unsigned)f2b(ya[3][k]) << 16);
                *(uint2*)(yrow + k*128 + c0) = pk;
            }
        }
    }
}

// ---------------- DISCO GEMM: D[n][co] = Y_t @ W^T, no LDS ----------------
// grid 512 blocks (XCD-swizzled (nt 128, coh 2, b 2)), 256 thr (4 waves 2n x 2co).
__global__ __launch_bounds__(256) void k_dgemm(
    const unsigned short* __restrict__ Yt, const unsigned short* __restrict__ wbf,
    const float* __restrict__ bias,
    float* __restrict__ xdown, float* __restrict__ part)
{
    const int flat = blockIdx.x + 128*(blockIdx.y + 2*blockIdx.z);
    const int rem  = (flat & 7)*64 + (flat >> 3);      // XCD-contiguous remap (512 = 8*64)
    const int coh  = rem & 1;
    const int nt   = (rem >> 1) & 127;
    const int b    = rem >> 8;

    const int t = threadIdx.x;
    const int w = t >> 6, l = t & 63;
    const int lr = l & 15, lk = l >> 4;
    const int wn2 = w >> 1, wc = w & 1;

    const int n0  = nt*128 + wn2*64;                   // per-batch n' base of wave
    const int co0 = coh*128 + wc*64;

    const unsigned short* pa[4];
    const unsigned short* pb[4];
    #pragma unroll
    for (int i = 0; i < 4; ++i)
        pa[i] = Yt + (size_t)(b*NPB + n0 + i*16 + lr)*896 + lk*8;
    #pragma unroll
    for (int j = 0; j < 4; ++j)
        pb[j] = wbf + (size_t)(co0 + j*16 + lr)*896 + lk*8;

    f32x4 acc[4][4];
    #pragma unroll
    for (int i = 0; i < 4; ++i)
        #pragma unroll
        for (int j = 0; j < 4; ++j) acc[i][j] = (f32x4)0.f;

    #pragma unroll 2
    for (int ks = 0; ks < 28; ++ks){
        bf16x8 af[4], bf[4];
        #pragma unroll
        for (int i = 0; i < 4; ++i)
            af[i] = __builtin_bit_cast(bf16x8, *(const uint4*)(pa[i] + ks*32));
        #pragma unroll
        for (int j = 0; j < 4; ++j)
            bf[j] = __builtin_bit_cast(bf16x8, *(const uint4*)(pb[j] + ks*32));
        #pragma unroll
        for (int i = 0; i < 4; ++i)
            #pragma unroll
            for (int j = 0; j < 4; ++j)
                acc[i][j] = __builtin_amdgcn_mfma_f32_16x16x32_bf16(af[i], bf[j], acc[i][j], 0, 0, 0);
    }

    // epilogue: bias, store (n-masked), GN2 partials
    float s[2] = {0.f, 0.f}, ss[2] = {0.f, 0.f};
    #pragma unroll
    for (int j = 0; j < 4; ++j){
        const int co = co0 + j*16 + lr;
        const float bv = bias[co];
        float* outp = xdown + (size_t)(b*256 + co)*NPB;
        const int jp = j >> 1;
        #pragma unroll
        for (int i = 0; i < 4; ++i){
            const int nb = n0 + i*16 + lk*4;
            if (nb < NPB){
                float4 o;
                o.x = acc[i][j][0] + bv; o.y = acc[i][j][1] + bv;
                o.z = acc[i][j][2] + bv; o.w = acc[i][j][3] + bv;
                *(float4*)(outp + nb) = o;
                s[jp]  += o.x + o.y + o.z + o.w;
                ss[jp] += o.x*o.x + o.y*o.y + o.z*o.z + o.w*o.w;
            }
        }
    }
    #pragma unroll
    for (int off = 32; off; off >>= 1){
        s[0] += __shfl_down(s[0], off); ss[0] += __shfl_down(ss[0], off);
        s[1] += __shfl_down(s[1], off); ss[1] += __shfl_down(ss[1], off);
    }
    if (l == 0){
        const int bid = (b*2 + coh)*128 + nt;
        part[(bid*8 + w*2 + 0)*2]     = s[0];
        part[(bid*8 + w*2 + 0)*2 + 1] = ss[0];
        part[(bid*8 + w*2 + 1)*2]     = s[1];
        part[(bid*8 + w*2 + 1)*2 + 1] = ss[1];
    }
}

// ---------------- GN2 finalize (split path) ----------------
// group g = coh*4 + wc*2 + jp;  slots over (nt 128, wn2 2)
__global__ __launch_bounds__(256) void k_gn2_final_s(const float* __restrict__ part,
                                                     float* __restrict__ stat){
    const int bg = blockIdx.x, b = bg >> 3, g = bg & 7, t = threadIdx.x;
    const int coh = g >> 2, wc = (g >> 1) & 1, jp = g & 1;
    const int nt = t & 127, wn2 = t >> 7;
    const int bid = (b*2 + coh)*128 + nt;
    const int slot = (wn2*2 + wc)*2 + jp;
    float s  = part[(bid*8 + slot)*2];
    float ss = part[(bid*8 + slot)*2 + 1];
    #pragma unroll
    for (int off = 32; off; off >>= 1){ s += __shfl_down(s, off); ss += __shfl_down(ss, off); }
    __shared__ float ls[4][2];
    if ((t & 63) == 0){ ls[t>>6][0] = s; ls[t>>6][1] = ss; }
    __syncthreads();
    if (t == 0){
        s  = ls[0][0] + ls[1][0] + ls[2][0] + ls[3][0];
        ss = ls[0][1] + ls[1][1] + ls[2][1] + ls[3][1];
        float m = s / (float)N_GN2;
        float v = ss / (float)N_GN2 - m*m;
        stat[bg*2]     = m;
        stat[bg*2 + 1] = 1.0f / sqrtf(v + 1e-5f);
    }
}

// ================= FALLBACK (round-3 fused disco) =================
__global__ __launch_bounds__(256, 2) void k_disco_fb(
    const float* __restrict__ skip,
    const float* __restrict__ psi_v, const int* __restrict__ psi_hi, const int* __restrict__ psi_wi,
    const unsigned short* __restrict__ wbf, const float* __restrict__ bias,
    float* __restrict__ xdown, float* __restrict__ part)
{
    __shared__ unsigned short yT[96*256];

    const int t   = threadIdx.x;
    const int woh = blockIdx.x;
    const int ho  = blockIdx.y;
    const int z   = blockIdx.z;
    const int b   = z >> 1, coh = z & 1;
    const int co0 = coh * 128;
    const int wo0 = woh * 90;

    const int w  = t >> 6;
    const int l  = t & 63;
    const int wm = w >> 1, wn = w & 1;

    const int wol = t & 31;
    const int cq  = t >> 5;
    const unsigned sw = (unsigned)(wol & 7) << 4;

    const float* skipb = skip + (size_t)b * (128*HW);

    f32x4 acc[4][3];
    #pragma unroll
    for (int m = 0; m < 4; ++m)
        #pragma unroll
        for (int nf = 0; nf < 3; ++nf) acc[m][nf] = (f32x4)0.f;

    #pragma unroll 1
    for (int cc = 0; cc < 4; ++cc){
        __syncthreads();
        const float* bp0 = skipb + (size_t)(cc*32 + cq*4 + 0)*HW;
        const float* bp1 = skipb + (size_t)(cc*32 + cq*4 + 1)*HW;
        const float* bp2 = skipb + (size_t)(cc*32 + cq*4 + 2)*HW;
        const float* bp3 = skipb + (size_t)(cc*32 + cq*4 + 3)*HW;

        float ya[3][4][7];
        #pragma unroll
        for (int wj = 0; wj < 3; ++wj)
            #pragma unroll
            for (int ci = 0; ci < 4; ++ci)
                #pragma unroll
                for (int k = 0; k < 7; ++k) ya[wj][ci][k] = 0.f;

        #pragma unroll 2
        for (int n = 0; n < NNZ; ++n){
            const int hi = psi_hi[ho*NNZ + n];
            const int wi = psi_wi[ho*NNZ + n];
            float ps[7];
            #pragma unroll
            for (int k = 0; k < 7; ++k) ps[k] = psi_v[(k*HOUT + ho)*NNZ + n];
            const int rowb = hi * WIN;
            #pragma unroll
            for (int wj = 0; wj < 3; ++wj){
                int wv = wi + 2*(wo0 + wol + 32*wj);
                wv = (wv >= 720) ? (wv - 720) : (wv >= 360 ? (wv - 360) : wv);
                const int off = rowb + wv;
                float g0 = bp0[off], g1 = bp1[off], g2 = bp2[off], g3 = bp3[off];
                #pragma unroll
                for (int k = 0; k < 7; ++k){
                    float pv = ps[k];
                    ya[wj][0][k] += pv*g0; ya[wj][1][k] += pv*g1;
                    ya[wj][2][k] += pv*g2; ya[wj][3][k] += pv*g3;
                }
            }
        }
        #pragma unroll
        for (int wj = 0; wj < 3; ++wj){
            char* row = (char*)yT + (wol + 32*wj)*512;
            #pragma unroll
            for (int k = 0; k < 7; ++k){
                unsigned base = ((unsigned)(k*64 + cq*8)) ^ sw;
                unsigned p0 = (unsigned)f2b(ya[wj][0][k]) | ((unsigned)f2b(ya[wj][1][k]) << 16);
                unsigned p1 = (unsigned)f2b(ya[wj][2][k]) | ((unsigned)f2b(ya[wj][3][k]) << 16);
                *(unsigned*)(row + base)     = p0;
                *(unsigned*)(row + base + 4) = p1;
            }
        }
        __syncthreads();

        const unsigned short* wrow = wbf + (size_t)(co0 + wm*64 + (l & 15))*896
                                         + cc*32 + ((l >> 4) << 3);
        #pragma unroll
        for (int k = 0; k < 7; ++k){
            bf16x8 af[4];
            #pragma unroll
            for (int m = 0; m < 4; ++m)
                af[m] = __builtin_bit_cast(bf16x8,
                          *(const uint4*)(wrow + (size_t)m*16*896 + k*128));
            bf16x8 bfv[3];
            #pragma unroll
            for (int nf = 0; nf < 3; ++nf){
                const int wo_l = wn*48 + nf*16 + (l & 15);
                unsigned off = (unsigned)(wo_l*512)
                             + (((unsigned)(k*64) + ((unsigned)(l >> 4) << 4))
                                ^ ((unsigned)(wo_l & 7) << 4));
                bfv[nf] = __builtin_bit_cast(bf16x8, *(const uint4*)((const char*)yT + off));
            }
            #pragma unroll
            for (int m = 0; m < 4; ++m)
                #pragma unroll
                for (int nf = 0; nf < 3; ++nf)
                    acc[m][nf] = __builtin_amdgcn_mfma_f32_16x16x32_bf16(af[m], bfv[nf], acc[m][nf], 0, 0, 0);
        }
    }

    float s[2] = {0.f, 0.f}, ss[2] = {0.f, 0.f};
    #pragma unroll
    for (int m = 0; m < 4; ++m){
        const int pair = m >> 1;
        const int cob = co0 + wm*64 + m*16 + ((l >> 4) << 2);
        float4 bv = *(const float4*)(bias + cob);
        #pragma unroll
        for (int nf = 0; nf < 3; ++nf){
            const int wo_t = wn*48 + nf*16 + (l & 15);
            if (wo_t < 90){
                #pragma unroll
                for (int r = 0; r < 4; ++r){
                    float v = acc[m][nf][r] + ((const float*)&bv)[r];
                    xdown[((size_t)(b*256 + cob + r)*HOUT + ho)*WOUT + wo0 + wo_t] = v;
                    s[pair] += v; ss[pair] += v*v;
                }
            }
        }
    }
    #pragma unroll
    for (int off = 32; off; off >>= 1){
        s[0] += __shfl_down(s[0], off); ss[0] += __shfl_down(ss[0], off);
        s[1] += __shfl_down(s[1], off); ss[1] += __shfl_down(ss[1], off);
    }
    if (l == 0){
        const int tid = (z*91 + ho)*2 + woh;
        part[(tid*8 + w*2 + 0)*2]     = s[0];
        part[(tid*8 + w*2 + 0)*2 + 1] = ss[0];
        part[(tid*8 + w*2 + 1)*2]     = s[1];
        part[(tid*8 + w*2 + 1)*2 + 1] = ss[1];
    }
}

__global__ __launch_bounds__(256) void k_gn2_final_fb(const float* __restrict__ part,
                                                      float* __restrict__ stat){
    const int bg = blockIdx.x, b = bg >> 3, g = bg & 7, t = threadIdx.x;
    const int coh = g >> 2, gl = g & 3, wm = gl >> 1, pair = gl & 1;
    float s = 0.f, ss = 0.f;
    for (int i = t; i < 364; i += 256){
        int ho = i >> 2, r = i & 3, woh = r >> 1, wn = r & 1;
        int tid = (((b*2 + coh)*91 + ho)*2 + woh);
        int slot = (wm*2 + wn)*2 + pair;
        s  += part[(tid*8 + slot)*2];
        ss += part[(tid*8 + slot)*2 + 1];
    }
    #pragma unroll
    for (int off = 32; off; off >>= 1){ s += __shfl_down(s, off); ss += __shfl_down(ss, off); }
    __shared__ float ls[4][2];
    if ((t & 63) == 0){ ls[t>>6][0] = s; ls[t>>6][1] = ss; }
    __syncthreads();
    if (t == 0){
        s  = ls[0][0] + ls[1][0] + ls[2][0] + ls[3][0];
        ss = ls[0][1] + ls[1][1] + ls[2][1] + ls[3][1];
        float m = s / (float)N_GN2;
        float v = ss / (float)N_GN2 - m*m;
        stat[bg*2]     = m;
        stat[bg*2 + 1] = 1.0f / sqrtf(v + 1e-5f);
    }
}

// ---------------- GN2 apply + gelu (in place) ----------------
__global__ __launch_bounds__(256) void k_gn2_apply(float* __restrict__ xd,
                                                   const float* __restrict__ stat,
                                                   const float* __restrict__ g2a,
                                                   const float* __restrict__ be2){
    const int gid = blockIdx.x*256 + threadIdx.x;
    const int stride = gridDim.x*256;
    for (int v = gid; v < 2096640; v += stride){
        float4 q = ((float4*)xd)[v];
        int i  = v << 2;
        int bc = i / 16380;
        int co = bc & 255, b = bc >> 8;
        float m  = stat[(b*8 + (co >> 5))*2];
        float r  = stat[(b*8 + (co >> 5))*2 + 1];
        float ga = g2a[co], be = be2[co];
        q.x = gelu_f((q.x - m)*r*ga + be);
        q.y = gelu_f((q.y - m)*r*ga + be);
        q.z = gelu_f((q.z - m)*r*ga + be);
        q.w = gelu_f((q.w - m)*r*ga + be);
        ((float4*)xd)[v] = q;
    }
}

extern "C" void kernel_launch(void* const* d_in, const int* in_sizes, int n_in,
                              void* d_out, int out_size, void* d_ws, size_t ws_size,
                              hipStream_t stream){
    const float* x      = (const float*)d_in[0];
    const float* psi_v  = (const float*)d_in[1];
    const int*   psi_hi = (const int*)d_in[2];
    const int*   psi_wi = (const int*)d_in[3];
    const float* weight = (const float*)d_in[4];
    const float* bias   = (const float*)d_in[5];
    const float* g1     = (const float*)d_in[6];
    const float* be1    = (const float*)d_in[7];
    const float* w1     = (const float*)d_in[8];
    const float* b1     = (const float*)d_in[9];
    const float* w2     = (const float*)d_in[10];
    const float* b2     = (const float*)d_in[11];
    const float* g2     = (const float*)d_in[12];
    const float* be2    = (const float*)d_in[13];

    float* skip  = (float*)d_out;
    float* xdown = skip + 16680960;          // 2*128*181*360

    float* ws       = (float*)d_ws;
    float* gn1_part = ws;                    // 4096 f
    float* gn1_stat = ws + 4096;             // 32
    float* gn2_part = ws + 4128;             // 11648 (covers both layouts)
    float* gn2_stat = ws + 15776;            // 32
    unsigned short* wbf = (unsigned short*)(ws + 15808);   // 229376 us
    unsigned short* w1b = (unsigned short*)(ws + 130496);  // 32768 us
    unsigned short* w2b = (unsigned short*)(ws + 146880);  // 32768 us
    unsigned short* sbf = (unsigned short*)(ws + 163264);  // 16,680,960 us
    unsigned short* Yt  = (unsigned short*)(ws + 8503744); // 29,360,128 us
    const size_t need = (8503744ull + 14680064ull) * 4ull; // ~92.7 MB

    const bool split = (ws_size >= need);

    k_gn1_partial<<<dim3(128, 16), 256, 0, stream>>>(x, gn1_part);
    k_gn1_final  <<<16, 128, 0, stream>>>(gn1_part, gn1_stat);
    k_wcvt       <<<256, 256, 0, stream>>>(weight, wbf);
    k_wcvt_mlp   <<<128, 256, 0, stream>>>(w1, w2, w1b, w2b);
    k_mlp        <<<dim3(1019, 2), 256, 0, stream>>>(x, gn1_stat, g1, be1, w1b, b1, w2b, b2,
                                                     skip, split ? sbf : (unsigned short*)nullptr);
    if (split){
        k_ybuild   <<<dim3(6, 91, 2), 256, 0, stream>>>(sbf, psi_v, psi_hi, psi_wi, Yt);
        k_dgemm    <<<dim3(128, 2, 2), 256, 0, stream>>>(Yt, wbf, bias, xdown, gn2_part);
        k_gn2_final_s<<<16, 256, 0, stream>>>(gn2_part, gn2_stat);
    } else {
        k_disco_fb <<<dim3(2, 91, 4), 256, 0, stream>>>(skip, psi_v, psi_hi, psi_wi,
                                                        wbf, bias, xdown, gn2_part);
        k_gn2_final_fb<<<16, 256, 0, stream>>>(gn2_part, gn2_stat);
    }
    k_gn2_apply  <<<2048, 256, 0, stream>>>(xdown, gn2_stat, g2, be2);
}

// Round 5
// 211.431 us; speedup vs baseline: 4.0876x; 1.0729x over previous
//
#include <hip/hip_runtime.h>

// DiscoDownBlock: GN1 -> 1x1 MLP (expand/gelu/project) + residual -> DISCO S2 conv
//                 -> GN2 -> gelu.  Outputs: skip [2,128,181,360], x_down [2,256,91,180]
//
// Round 5: k_mlp VALU trim.
//  - per-block (a,b) GN1 LUT: staging is 1 FMA/element, no per-element stat loads.
//  - all bf16 packs via hardware (__bf16) casts (v_cvt_pk_bf16_f32), not bit math.
//  - launch_bounds(256,3) for 3 blocks/CU (LDS 49KB allows 3).

#define HW      65160      // 181*360
#define HIN     181
#define WIN     360
#define HOUT    91
#define WOUT    180
#define CIN     128
#define COUT    256
#define KB      7
#define NNZ     16
#define N_GN1   1042560    // 16*HW
#define N_GN2   524160     // 32*91*180
#define NPB     16380      // 91*180 (per-batch n)

typedef float  f32x4  __attribute__((ext_vector_type(4)));
typedef __bf16 bf16x8 __attribute__((ext_vector_type(8)));

__device__ __forceinline__ unsigned short f2b(float v){
    return __builtin_bit_cast(unsigned short, (__bf16)v);
}
__device__ __forceinline__ unsigned pkbf(float a, float b){
    return (unsigned)__builtin_bit_cast(unsigned short, (__bf16)a)
         | ((unsigned)__builtin_bit_cast(unsigned short, (__bf16)b) << 16);
}
__device__ __forceinline__ float blo(unsigned u){ return __uint_as_float(u << 16); }
__device__ __forceinline__ float bhi(unsigned u){ return __uint_as_float(u & 0xffff0000u); }

// tanh-approx gelu (matches jax.nn.gelu approximate=True), overflow-safe
__device__ __forceinline__ float gelu_f(float v){
    float z  = 0.7978845608028654f * (v + 0.044715f * v * v * v);
    float az = fabsf(z);
    float e  = __expf(-2.0f * az);
    float th = (1.0f - e) / (1.0f + e);
    th = copysignf(th, z);
    return 0.5f * v * (1.0f + th);
}

// ---------------- GN1 stats ----------------
__global__ __launch_bounds__(256) void k_gn1_partial(const float* __restrict__ x,
                                                     float* __restrict__ part){
    const int bg = blockIdx.y, blk = blockIdx.x, t = threadIdx.x;
    const float4* p4 = (const float4*)(x + (size_t)bg * N_GN1);
    float s = 0.f, ss = 0.f;
    for (int v = blk*256 + t; v < N_GN1/4; v += 128*256){
        float4 q = p4[v];
        s  += q.x + q.y + q.z + q.w;
        ss += q.x*q.x + q.y*q.y + q.z*q.z + q.w*q.w;
    }
    #pragma unroll
    for (int off = 32; off; off >>= 1){ s += __shfl_down(s, off); ss += __shfl_down(ss, off); }
    __shared__ float ls[4][2];
    if ((t & 63) == 0){ ls[t>>6][0] = s; ls[t>>6][1] = ss; }
    __syncthreads();
    if (t == 0){
        s  = ls[0][0] + ls[1][0] + ls[2][0] + ls[3][0];
        ss = ls[0][1] + ls[1][1] + ls[2][1] + ls[3][1];
        part[(bg*128 + blk)*2]     = s;
        part[(bg*128 + blk)*2 + 1] = ss;
    }
}

__global__ __launch_bounds__(128) void k_gn1_final(const float* __restrict__ part,
                                                   float* __restrict__ stat){
    const int bg = blockIdx.x, t = threadIdx.x;
    float s  = part[(bg*128 + t)*2];
    float ss = part[(bg*128 + t)*2 + 1];
    #pragma unroll
    for (int off = 32; off; off >>= 1){ s += __shfl_down(s, off); ss += __shfl_down(ss, off); }
    __shared__ float ls[2][2];
    if ((t & 63) == 0){ ls[t>>6][0] = s; ls[t>>6][1] = ss; }
    __syncthreads();
    if (t == 0){
        s  = ls[0][0] + ls[1][0];
        ss = ls[0][1] + ls[1][1];
        float m = s / (float)N_GN1;
        float v = ss / (float)N_GN1 - m*m;
        stat[bg*2]     = m;
        stat[bg*2 + 1] = 1.0f / sqrtf(v + 1e-5f);
    }
}

// ---------------- weight converts ----------------
__global__ __launch_bounds__(256) void k_wcvt(const float* __restrict__ wsrc,
                                              unsigned short* __restrict__ wbf){
    const int co = blockIdx.x;
    const int t = threadIdx.x;
    for (int r = t; r < 896; r += 256){
        int k = r >> 7, c = r & 127;
        wbf[co*896 + r] = f2b(wsrc[co*896 + c*7 + k]);
    }
}

__global__ __launch_bounds__(256) void k_wcvt_mlp(const float* __restrict__ w1,
                                                  const float* __restrict__ w2,
                                                  unsigned short* __restrict__ w1b,
                                                  unsigned short* __restrict__ w2b){
    const int i = blockIdx.x*256 + threadIdx.x;
    if (i < 32768){
        w1b[i] = f2b(w1[i]);
        w2b[i] = f2b(w2[i]);
    }
}

// ---------------- fused MLP + residual (MFMA) ----------------
// grid (1019, 2), 256 thr (4 waves). 64-pixel tile.
__global__ __launch_bounds__(256, 3) void k_mlp(
    const float* __restrict__ x, const float* __restrict__ stat,
    const float* __restrict__ g1, const float* __restrict__ be1,
    const unsigned short* __restrict__ w1b, const float* __restrict__ b1,
    const unsigned short* __restrict__ w2b, const float* __restrict__ b2,
    float* __restrict__ skip, unsigned short* __restrict__ sbf)
{
    __shared__ unsigned short xns[64*128];
    __shared__ unsigned short h1s[64*256];
    __shared__ float aL[128], bL[128];

    const int t = threadIdx.x;
    const int b = blockIdx.y;
    const int pix0 = blockIdx.x * 64;
    const int valid = min(64, HW - pix0);

    const int w  = t >> 6, l = t & 63;
    const int lr = l & 15, lk = l >> 4;

    // GN1 scale/shift LUT (one FMA per staged element afterwards)
    if (t < 128){
        const int c = t;
        float m = stat[(b*8 + (c >> 4))*2];
        float r = stat[(b*8 + (c >> 4))*2 + 1];
        float a = r * g1[c];
        aL[c] = a;
        bL[c] = be1[c] - m*a;
    }
    __syncthreads();

    { // stage normalized xn tile: thread (p = l, c-block = w*32..+32)
        const int p = l;
        const unsigned sw = ((unsigned)(p & 7)) << 4;
        const float* xb = x + (size_t)b*128*HW + pix0 + p;
        #pragma unroll
        for (int i = 0; i < 8; ++i){
            const int c0 = w*32 + i*4;
            uint2 pk;
            if (p < valid){
                float v0 = __builtin_fmaf(xb[(size_t)(c0+0)*HW], aL[c0+0], bL[c0+0]);
                float v1 = __builtin_fmaf(xb[(size_t)(c0+1)*HW], aL[c0+1], bL[c0+1]);
                float v2 = __builtin_fmaf(xb[(size_t)(c0+2)*HW], aL[c0+2], bL[c0+2]);
                float v3 = __builtin_fmaf(xb[(size_t)(c0+3)*HW], aL[c0+3], bL[c0+3]);
                pk.x = pkbf(v0, v1); pk.y = pkbf(v2, v3);
            } else { pk.x = 0u; pk.y = 0u; }
            *(uint2*)((char*)xns + p*256 + (((unsigned)(c0*2)) ^ sw)) = pk;
        }
    }
    __syncthreads();

    // GEMM1: h1[oc][p] = gelu(w1 @ xn + b1); wave owns oc block w*64..+64
    {
        f32x4 acc[4][4];
        #pragma unroll
        for (int m = 0; m < 4; ++m){
            float4 bv = *(const float4*)(b1 + w*64 + m*16 + lk*4);
            #pragma unroll
            for (int nf = 0; nf < 4; ++nf) acc[m][nf] = __builtin_bit_cast(f32x4, bv);
        }
        const unsigned short* wr = w1b + (size_t)(w*64 + lr)*128 + lk*8;
        #pragma unroll
        for (int ks = 0; ks < 4; ++ks){
            bf16x8 af[4];
            #pragma unroll
            for (int m = 0; m < 4; ++m)
                af[m] = __builtin_bit_cast(bf16x8, *(const uint4*)(wr + m*16*128 + ks*32));
            bf16x8 bfv[4];
            #pragma unroll
            for (int nf = 0; nf < 4; ++nf){
                const int p = nf*16 + lr;
                unsigned off = (unsigned)(p*256)
                             + (((unsigned)(ks*64 + lk*16)) ^ (((unsigned)(p & 7)) << 4));
                bfv[nf] = __builtin_bit_cast(bf16x8, *(const uint4*)((const char*)xns + off));
            }
            #pragma unroll
            for (int m = 0; m < 4; ++m)
                #pragma unroll
                for (int nf = 0; nf < 4; ++nf)
                    acc[m][nf] = __builtin_amdgcn_mfma_f32_16x16x32_bf16(af[m], bfv[nf], acc[m][nf], 0, 0, 0);
        }
        #pragma unroll
        for (int m = 0; m < 4; ++m){
            const int oc0 = w*64 + m*16 + lk*4;
            #pragma unroll
            for (int nf = 0; nf < 4; ++nf){
                const int p = nf*16 + lr;
                uint2 pk;
                pk.x = pkbf(gelu_f(acc[m][nf][0]), gelu_f(acc[m][nf][1]));
                pk.y = pkbf(gelu_f(acc[m][nf][2]), gelu_f(acc[m][nf][3]));
                unsigned off = (unsigned)(p*512)
                             + (((unsigned)(oc0*2)) ^ (((unsigned)(p & 7)) << 4));
                *(uint2*)((char*)h1s + off) = pk;
            }
        }
    }
    __syncthreads();

    // GEMM2 + residual (+ bf16 transposed copy for the gather stage)
    {
        f32x4 acc[2][4];
        #pragma unroll
        for (int m = 0; m < 2; ++m){
            float4 bv = *(const float4*)(b2 + w*32 + m*16 + lk*4);
            #pragma unroll
            for (int nf = 0; nf < 4; ++nf) acc[m][nf] = __builtin_bit_cast(f32x4, bv);
        }
        const unsigned short* wr = w2b + (size_t)(w*32 + lr)*256 + lk*8;
        #pragma unroll
        for (int ks = 0; ks < 8; ++ks){
            bf16x8 af[2];
            #pragma unroll
            for (int m = 0; m < 2; ++m)
                af[m] = __builtin_bit_cast(bf16x8, *(const uint4*)(wr + m*16*256 + ks*32));
            bf16x8 bfv[4];
            #pragma unroll
            for (int nf = 0; nf < 4; ++nf){
                const int p = nf*16 + lr;
                unsigned off = (unsigned)(p*512)
                             + (((unsigned)(ks*64 + lk*16)) ^ (((unsigned)(p & 7)) << 4));
                bfv[nf] = __builtin_bit_cast(bf16x8, *(const uint4*)((const char*)h1s + off));
            }
            #pragma unroll
            for (int m = 0; m < 2; ++m)
                #pragma unroll
                for (int nf = 0; nf < 4; ++nf)
                    acc[m][nf] = __builtin_amdgcn_mfma_f32_16x16x32_bf16(af[m], bfv[nf], acc[m][nf], 0, 0, 0);
        }
        #pragma unroll
        for (int m = 0; m < 2; ++m){
            const int c0 = w*32 + m*16 + lk*4;
            #pragma unroll
            for (int nf = 0; nf < 4; ++nf){
                const int p = nf*16 + lr;
                if (p < valid){
                    float o[4];
                    size_t base = (size_t)(b*128 + c0)*HW + pix0 + p;
                    #pragma unroll
                    for (int r = 0; r < 4; ++r){
                        float vv = acc[m][nf][r] + x[base + (size_t)r*HW];
                        skip[base + (size_t)r*HW] = vv;
                        o[r] = vv;
                    }
                    if (sbf){
                        uint2 pk;
                        pk.x = pkbf(o[0], o[1]);
                        pk.y = pkbf(o[2], o[3]);
                        *(uint2*)(sbf + ((size_t)b*HW + pix0 + p)*128 + c0) = pk;
                    }
                }
            }
        }
    }
}

// ---------------- Y build: gather + psi reduce -> Y_t[n][ck] bf16 ----------------
// grid (6 wo-tiles of 32, 91 ho, 2 b), 256 thr = 32 wol x 8 cq.
__global__ __launch_bounds__(256) void k_ybuild(
    const unsigned short* __restrict__ sbf,
    const float* __restrict__ psi_v, const int* __restrict__ psi_hi, const int* __restrict__ psi_wi,
    unsigned short* __restrict__ Yt)
{
    __shared__ int   offh[16];
    __shared__ int   wis[16];
    __shared__ float psis[112];

    const int t   = threadIdx.x;
    const int wot = blockIdx.x, ho = blockIdx.y, b = blockIdx.z;

    if (t < 112) psis[t] = psi_v[((t >> 4)*HOUT + ho)*NNZ + (t & 15)];
    if (t < 16){ offh[t] = psi_hi[ho*NNZ + t] * WIN; wis[t] = psi_wi[ho*NNZ + t]; }
    __syncthreads();

    const int wol = t >> 3, cq = t & 7;
    const int wo  = wot*32 + wol;
    const bool valid = (wo < WOUT);
    const int wo_c = valid ? wo : (WOUT - 1);

    int offs[16];
    #pragma unroll
    for (int n = 0; n < 16; ++n){
        int wv = wis[n] + 2*wo_c;
        wv = (wv >= WIN) ? (wv - WIN) : wv;
        offs[n] = offh[n] + wv;
    }

    const unsigned short* sb = sbf + (size_t)b * HW * 128;
    unsigned short* yrow = Yt + (size_t)(b*NPB + ho*WOUT + wo_c) * 896;

    #pragma unroll 1
    for (int cc = 0; cc < 4; ++cc){
        const int c0 = cc*32 + cq*4;
        float ya[4][7];
        #pragma unroll
        for (int ci = 0; ci < 4; ++ci)
            #pragma unroll
            for (int k = 0; k < 7; ++k) ya[ci][k] = 0.f;

        #pragma unroll 2
        for (int n = 0; n < 16; ++n){
            uint2 q = *(const uint2*)(sb + (size_t)offs[n]*128 + c0);
            float g0 = blo(q.x), g1 = bhi(q.x), g2 = blo(q.y), g3 = bhi(q.y);
            #pragma unroll
            for (int k = 0; k < 7; ++k){
                float pv = psis[k*16 + n];
                ya[0][k] += pv*g0; ya[1][k] += pv*g1;
                ya[2][k] += pv*g2; ya[3][k] += pv*g3;
            }
        }
        if (valid){
            #pragma unroll
            for (int k = 0; k < 7; ++k){
                uint2 pk;
                pk.x = pkbf(ya[0][k], ya[1][k]);
                pk.y = pkbf(ya[2][k], ya[3][k]);
                *(uint2*)(yrow + k*128 + c0) = pk;
            }
        }
    }
}

// ---------------- DISCO GEMM: D[n][co] = Y_t @ W^T, no LDS ----------------
__global__ __launch_bounds__(256) void k_dgemm(
    const unsigned short* __restrict__ Yt, const unsigned short* __restrict__ wbf,
    const float* __restrict__ bias,
    float* __restrict__ xdown, float* __restrict__ part)
{
    const int flat = blockIdx.x + 128*(blockIdx.y + 2*blockIdx.z);
    const int rem  = (flat & 7)*64 + (flat >> 3);
    const int coh  = rem & 1;
    const int nt   = (rem >> 1) & 127;
    const int b    = rem >> 8;

    const int t = threadIdx.x;
    const int w = t >> 6, l = t & 63;
    const int lr = l & 15, lk = l >> 4;
    const int wn2 = w >> 1, wc = w & 1;

    const int n0  = nt*128 + wn2*64;
    const int co0 = coh*128 + wc*64;

    const unsigned short* pa[4];
    const unsigned short* pb[4];
    #pragma unroll
    for (int i = 0; i < 4; ++i)
        pa[i] = Yt + (size_t)(b*NPB + n0 + i*16 + lr)*896 + lk*8;
    #pragma unroll
    for (int j = 0; j < 4; ++j)
        pb[j] = wbf + (size_t)(co0 + j*16 + lr)*896 + lk*8;

    f32x4 acc[4][4];
    #pragma unroll
    for (int i = 0; i < 4; ++i)
        #pragma unroll
        for (int j = 0; j < 4; ++j) acc[i][j] = (f32x4)0.f;

    #pragma unroll 2
    for (int ks = 0; ks < 28; ++ks){
        bf16x8 af[4], bf[4];
        #pragma unroll
        for (int i = 0; i < 4; ++i)
            af[i] = __builtin_bit_cast(bf16x8, *(const uint4*)(pa[i] + ks*32));
        #pragma unroll
        for (int j = 0; j < 4; ++j)
            bf[j] = __builtin_bit_cast(bf16x8, *(const uint4*)(pb[j] + ks*32));
        #pragma unroll
        for (int i = 0; i < 4; ++i)
            #pragma unroll
            for (int j = 0; j < 4; ++j)
                acc[i][j] = __builtin_amdgcn_mfma_f32_16x16x32_bf16(af[i], bf[j], acc[i][j], 0, 0, 0);
    }

    float s[2] = {0.f, 0.f}, ss[2] = {0.f, 0.f};
    #pragma unroll
    for (int j = 0; j < 4; ++j){
        const int co = co0 + j*16 + lr;
        const float bv = bias[co];
        float* outp = xdown + (size_t)(b*256 + co)*NPB;
        const int jp = j >> 1;
        #pragma unroll
        for (int i = 0; i < 4; ++i){
            const int nb = n0 + i*16 + lk*4;
            if (nb < NPB){
                float4 o;
                o.x = acc[i][j][0] + bv; o.y = acc[i][j][1] + bv;
                o.z = acc[i][j][2] + bv; o.w = acc[i][j][3] + bv;
                *(float4*)(outp + nb) = o;
                s[jp]  += o.x + o.y + o.z + o.w;
                ss[jp] += o.x*o.x + o.y*o.y + o.z*o.z + o.w*o.w;
            }
        }
    }
    #pragma unroll
    for (int off = 32; off; off >>= 1){
        s[0] += __shfl_down(s[0], off); ss[0] += __shfl_down(ss[0], off);
        s[1] += __shfl_down(s[1], off); ss[1] += __shfl_down(ss[1], off);
    }
    if (l == 0){
        const int bid = (b*2 + coh)*128 + nt;
        part[(bid*8 + w*2 + 0)*2]     = s[0];
        part[(bid*8 + w*2 + 0)*2 + 1] = ss[0];
        part[(bid*8 + w*2 + 1)*2]     = s[1];
        part[(bid*8 + w*2 + 1)*2 + 1] = ss[1];
    }
}

// ---------------- GN2 finalize (split path) ----------------
__global__ __launch_bounds__(256) void k_gn2_final_s(const float* __restrict__ part,
                                                     float* __restrict__ stat){
    const int bg = blockIdx.x, b = bg >> 3, g = bg & 7, t = threadIdx.x;
    const int coh = g >> 2, wc = (g >> 1) & 1, jp = g & 1;
    const int nt = t & 127, wn2 = t >> 7;
    const int bid = (b*2 + coh)*128 + nt;
    const int slot = (wn2*2 + wc)*2 + jp;
    float s  = part[(bid*8 + slot)*2];
    float ss = part[(bid*8 + slot)*2 + 1];
    #pragma unroll
    for (int off = 32; off; off >>= 1){ s += __shfl_down(s, off); ss += __shfl_down(ss, off); }
    __shared__ float ls[4][2];
    if ((t & 63) == 0){ ls[t>>6][0] = s; ls[t>>6][1] = ss; }
    __syncthreads();
    if (t == 0){
        s  = ls[0][0] + ls[1][0] + ls[2][0] + ls[3][0];
        ss = ls[0][1] + ls[1][1] + ls[2][1] + ls[3][1];
        float m = s / (float)N_GN2;
        float v = ss / (float)N_GN2 - m*m;
        stat[bg*2]     = m;
        stat[bg*2 + 1] = 1.0f / sqrtf(v + 1e-5f);
    }
}

// ================= FALLBACK (fused disco) =================
__global__ __launch_bounds__(256, 2) void k_disco_fb(
    const float* __restrict__ skip,
    const float* __restrict__ psi_v, const int* __restrict__ psi_hi, const int* __restrict__ psi_wi,
    const unsigned short* __restrict__ wbf, const float* __restrict__ bias,
    float* __restrict__ xdown, float* __restrict__ part)
{
    __shared__ unsigned short yT[96*256];

    const int t   = threadIdx.x;
    const int woh = blockIdx.x;
    const int ho  = blockIdx.y;
    const int z   = blockIdx.z;
    const int b   = z >> 1, coh = z & 1;
    const int co0 = coh * 128;
    const int wo0 = woh * 90;

    const int w  = t >> 6;
    const int l  = t & 63;
    const int wm = w >> 1, wn = w & 1;

    const int wol = t & 31;
    const int cq  = t >> 5;
    const unsigned sw = (unsigned)(wol & 7) << 4;

    const float* skipb = skip + (size_t)b * (128*HW);

    f32x4 acc[4][3];
    #pragma unroll
    for (int m = 0; m < 4; ++m)
        #pragma unroll
        for (int nf = 0; nf < 3; ++nf) acc[m][nf] = (f32x4)0.f;

    #pragma unroll 1
    for (int cc = 0; cc < 4; ++cc){
        __syncthreads();
        const float* bp0 = skipb + (size_t)(cc*32 + cq*4 + 0)*HW;
        const float* bp1 = skipb + (size_t)(cc*32 + cq*4 + 1)*HW;
        const float* bp2 = skipb + (size_t)(cc*32 + cq*4 + 2)*HW;
        const float* bp3 = skipb + (size_t)(cc*32 + cq*4 + 3)*HW;

        float ya[3][4][7];
        #pragma unroll
        for (int wj = 0; wj < 3; ++wj)
            #pragma unroll
            for (int ci = 0; ci < 4; ++ci)
                #pragma unroll
                for (int k = 0; k < 7; ++k) ya[wj][ci][k] = 0.f;

        #pragma unroll 2
        for (int n = 0; n < NNZ; ++n){
            const int hi = psi_hi[ho*NNZ + n];
            const int wi = psi_wi[ho*NNZ + n];
            float ps[7];
            #pragma unroll
            for (int k = 0; k < 7; ++k) ps[k] = psi_v[(k*HOUT + ho)*NNZ + n];
            const int rowb = hi * WIN;
            #pragma unroll
            for (int wj = 0; wj < 3; ++wj){
                int wv = wi + 2*(wo0 + wol + 32*wj);
                wv = (wv >= 720) ? (wv - 720) : (wv >= 360 ? (wv - 360) : wv);
                const int off = rowb + wv;
                float g0 = bp0[off], g1 = bp1[off], g2 = bp2[off], g3 = bp3[off];
                #pragma unroll
                for (int k = 0; k < 7; ++k){
                    float pv = ps[k];
                    ya[wj][0][k] += pv*g0; ya[wj][1][k] += pv*g1;
                    ya[wj][2][k] += pv*g2; ya[wj][3][k] += pv*g3;
                }
            }
        }
        #pragma unroll
        for (int wj = 0; wj < 3; ++wj){
            char* row = (char*)yT + (wol + 32*wj)*512;
            #pragma unroll
            for (int k = 0; k < 7; ++k){
                unsigned base = ((unsigned)(k*64 + cq*8)) ^ sw;
                *(unsigned*)(row + base)     = pkbf(ya[wj][0][k], ya[wj][1][k]);
                *(unsigned*)(row + base + 4) = pkbf(ya[wj][2][k], ya[wj][3][k]);
            }
        }
        __syncthreads();

        const unsigned short* wrow = wbf + (size_t)(co0 + wm*64 + (l & 15))*896
                                         + cc*32 + ((l >> 4) << 3);
        #pragma unroll
        for (int k = 0; k < 7; ++k){
            bf16x8 af[4];
            #pragma unroll
            for (int m = 0; m < 4; ++m)
                af[m] = __builtin_bit_cast(bf16x8,
                          *(const uint4*)(wrow + (size_t)m*16*896 + k*128));
            bf16x8 bfv[3];
            #pragma unroll
            for (int nf = 0; nf < 3; ++nf){
                const int wo_l = wn*48 + nf*16 + (l & 15);
                unsigned off = (unsigned)(wo_l*512)
                             + (((unsigned)(k*64) + ((unsigned)(l >> 4) << 4))
                                ^ ((unsigned)(wo_l & 7) << 4));
                bfv[nf] = __builtin_bit_cast(bf16x8, *(const uint4*)((const char*)yT + off));
            }
            #pragma unroll
            for (int m = 0; m < 4; ++m)
                #pragma unroll
                for (int nf = 0; nf < 3; ++nf)
                    acc[m][nf] = __builtin_amdgcn_mfma_f32_16x16x32_bf16(af[m], bfv[nf], acc[m][nf], 0, 0, 0);
        }
    }

    float s[2] = {0.f, 0.f}, ss[2] = {0.f, 0.f};
    #pragma unroll
    for (int m = 0; m < 4; ++m){
        const int pair = m >> 1;
        const int cob = co0 + wm*64 + m*16 + ((l >> 4) << 2);
        float4 bv = *(const float4*)(bias + cob);
        #pragma unroll
        for (int nf = 0; nf < 3; ++nf){
            const int wo_t = wn*48 + nf*16 + (l & 15);
            if (wo_t < 90){
                #pragma unroll
                for (int r = 0; r < 4; ++r){
                    float v = acc[m][nf][r] + ((const float*)&bv)[r];
                    xdown[((size_t)(b*256 + cob + r)*HOUT + ho)*WOUT + wo0 + wo_t] = v;
                    s[pair] += v; ss[pair] += v*v;
                }
            }
        }
    }
    #pragma unroll
    for (int off = 32; off; off >>= 1){
        s[0] += __shfl_down(s[0], off); ss[0] += __shfl_down(ss[0], off);
        s[1] += __shfl_down(s[1], off); ss[1] += __shfl_down(ss[1], off);
    }
    if (l == 0){
        const int tid = (z*91 + ho)*2 + woh;
        part[(tid*8 + w*2 + 0)*2]     = s[0];
        part[(tid*8 + w*2 + 0)*2 + 1] = ss[0];
        part[(tid*8 + w*2 + 1)*2]     = s[1];
        part[(tid*8 + w*2 + 1)*2 + 1] = ss[1];
    }
}

__global__ __launch_bounds__(256) void k_gn2_final_fb(const float* __restrict__ part,
                                                      float* __restrict__ stat){
    const int bg = blockIdx.x, b = bg >> 3, g = bg & 7, t = threadIdx.x;
    const int coh = g >> 2, gl = g & 3, wm = gl >> 1, pair = gl & 1;
    float s = 0.f, ss = 0.f;
    for (int i = t; i < 364; i += 256){
        int ho = i >> 2, r = i & 3, woh = r >> 1, wn = r & 1;
        int tid = (((b*2 + coh)*91 + ho)*2 + woh);
        int slot = (wm*2 + wn)*2 + pair;
        s  += part[(tid*8 + slot)*2];
        ss += part[(tid*8 + slot)*2 + 1];
    }
    #pragma unroll
    for (int off = 32; off; off >>= 1){ s += __shfl_down(s, off); ss += __shfl_down(ss, off); }
    __shared__ float ls[4][2];
    if ((t & 63) == 0){ ls[t>>6][0] = s; ls[t>>6][1] = ss; }
    __syncthreads();
    if (t == 0){
        s  = ls[0][0] + ls[1][0] + ls[2][0] + ls[3][0];
        ss = ls[0][1] + ls[1][1] + ls[2][1] + ls[3][1];
        float m = s / (float)N_GN2;
        float v = ss / (float)N_GN2 - m*m;
        stat[bg*2]     = m;
        stat[bg*2 + 1] = 1.0f / sqrtf(v + 1e-5f);
    }
}

// ---------------- GN2 apply + gelu (in place) ----------------
__global__ __launch_bounds__(256) void k_gn2_apply(float* __restrict__ xd,
                                                   const float* __restrict__ stat,
                                                   const float* __restrict__ g2a,
                                                   const float* __restrict__ be2){
    const int gid = blockIdx.x*256 + threadIdx.x;
    const int stride = gridDim.x*256;
    for (int v = gid; v < 2096640; v += stride){
        float4 q = ((float4*)xd)[v];
        int i  = v << 2;
        int bc = i / 16380;
        int co = bc & 255, b = bc >> 8;
        float m  = stat[(b*8 + (co >> 5))*2];
        float r  = stat[(b*8 + (co >> 5))*2 + 1];
        float ga = g2a[co], be = be2[co];
        q.x = gelu_f((q.x - m)*r*ga + be);
        q.y = gelu_f((q.y - m)*r*ga + be);
        q.z = gelu_f((q.z - m)*r*ga + be);
        q.w = gelu_f((q.w - m)*r*ga + be);
        ((float4*)xd)[v] = q;
    }
}

extern "C" void kernel_launch(void* const* d_in, const int* in_sizes, int n_in,
                              void* d_out, int out_size, void* d_ws, size_t ws_size,
                              hipStream_t stream){
    const float* x      = (const float*)d_in[0];
    const float* psi_v  = (const float*)d_in[1];
    const int*   psi_hi = (const int*)d_in[2];
    const int*   psi_wi = (const int*)d_in[3];
    const float* weight = (const float*)d_in[4];
    const float* bias   = (const float*)d_in[5];
    const float* g1     = (const float*)d_in[6];
    const float* be1    = (const float*)d_in[7];
    const float* w1     = (const float*)d_in[8];
    const float* b1     = (const float*)d_in[9];
    const float* w2     = (const float*)d_in[10];
    const float* b2     = (const float*)d_in[11];
    const float* g2     = (const float*)d_in[12];
    const float* be2    = (const float*)d_in[13];

    float* skip  = (float*)d_out;
    float* xdown = skip + 16680960;          // 2*128*181*360

    float* ws       = (float*)d_ws;
    float* gn1_part = ws;                    // 4096 f
    float* gn1_stat = ws + 4096;             // 32
    float* gn2_part = ws + 4128;             // 11648
    float* gn2_stat = ws + 15776;            // 32
    unsigned short* wbf = (unsigned short*)(ws + 15808);   // 229376 us
    unsigned short* w1b = (unsigned short*)(ws + 130496);  // 32768 us
    unsigned short* w2b = (unsigned short*)(ws + 146880);  // 32768 us
    unsigned short* sbf = (unsigned short*)(ws + 163264);  // 16,680,960 us
    unsigned short* Yt  = (unsigned short*)(ws + 8503744); // 29,360,128 us
    const size_t need = (8503744ull + 14680064ull) * 4ull; // ~92.7 MB

    const bool split = (ws_size >= need);

    k_gn1_partial<<<dim3(128, 16), 256, 0, stream>>>(x, gn1_part);
    k_gn1_final  <<<16, 128, 0, stream>>>(gn1_part, gn1_stat);
    k_wcvt       <<<256, 256, 0, stream>>>(weight, wbf);
    k_wcvt_mlp   <<<128, 256, 0, stream>>>(w1, w2, w1b, w2b);
    k_mlp        <<<dim3(1019, 2), 256, 0, stream>>>(x, gn1_stat, g1, be1, w1b, b1, w2b, b2,
                                                     skip, split ? sbf : (unsigned short*)nullptr);
    if (split){
        k_ybuild   <<<dim3(6, 91, 2), 256, 0, stream>>>(sbf, psi_v, psi_hi, psi_wi, Yt);
        k_dgemm    <<<dim3(128, 2, 2), 256, 0, stream>>>(Yt, wbf, bias, xdown, gn2_part);
        k_gn2_final_s<<<16, 256, 0, stream>>>(gn2_part, gn2_stat);
    } else {
        k_disco_fb <<<dim3(2, 91, 4), 256, 0, stream>>>(skip, psi_v, psi_hi, psi_wi,
                                                        wbf, bias, xdown, gn2_part);
        k_gn2_final_fb<<<16, 256, 0, stream>>>(gn2_part, gn2_stat);
    }
    k_gn2_apply  <<<2048, 256, 0, stream>>>(xdown, gn2_stat, g2, be2);
}

// Round 6
// 207.477 us; speedup vs baseline: 4.1655x; 1.0191x over previous
//
#include <hip/hip_runtime.h>

// DiscoDownBlock: GN1 -> 1x1 MLP (expand/gelu/project) + residual -> DISCO S2 conv
//                 -> GN2 -> gelu.  Outputs: skip [2,128,181,360], x_down [2,256,91,180]
//
// Round 6:
//  - gelu via sigmoid form (v * rcp(1+exp2(-2.885 z))): 8 VALU ops vs ~13.
//  - GEMM2 operand swap -> output C[p][c]: float4 skip stores + float4 residual
//    loads (p on register axis). Same LDS/global reads as before.
//  - xdown intermediate bf16 (overlaid on dead sbf region): dgemm writes 33MB
//    not 67; gn2_apply reads bf16, writes fp32 d_out.

#define HW      65160      // 181*360
#define HIN     181
#define WIN     360
#define HOUT    91
#define WOUT    180
#define CIN     128
#define COUT    256
#define KB      7
#define NNZ     16
#define N_GN1   1042560    // 16*HW
#define N_GN2   524160     // 32*91*180
#define NPB     16380      // 91*180 (per-batch n)

typedef float  f32x4  __attribute__((ext_vector_type(4)));
typedef __bf16 bf16x8 __attribute__((ext_vector_type(8)));

__device__ __forceinline__ unsigned short f2b(float v){
    return __builtin_bit_cast(unsigned short, (__bf16)v);
}
__device__ __forceinline__ unsigned pkbf(float a, float b){
    return (unsigned)__builtin_bit_cast(unsigned short, (__bf16)a)
         | ((unsigned)__builtin_bit_cast(unsigned short, (__bf16)b) << 16);
}
__device__ __forceinline__ float blo(unsigned u){ return __uint_as_float(u << 16); }
__device__ __forceinline__ float bhi(unsigned u){ return __uint_as_float(u & 0xffff0000u); }

// tanh-approx gelu via sigmoid identity: 0.5v(1+tanh z) = v * sigma(2z).
// e = exp2(-2*log2e*z); overflow-safe: e->inf => rcp->0 (v->-inf limit),
// e->0 => v. ~8 VALU ops.
__device__ __forceinline__ float gelu_f(float v){
    float z = v * __builtin_fmaf(0.0356774081363f, v*v, 0.7978845608028654f);
    float e = __builtin_amdgcn_exp2f(-2.8853900817779268f * z);
    return v * __builtin_amdgcn_rcpf(1.0f + e);
}

// ---------------- GN1 stats ----------------
__global__ __launch_bounds__(256) void k_gn1_partial(const float* __restrict__ x,
                                                     float* __restrict__ part){
    const int bg = blockIdx.y, blk = blockIdx.x, t = threadIdx.x;
    const float4* p4 = (const float4*)(x + (size_t)bg * N_GN1);
    float s = 0.f, ss = 0.f;
    for (int v = blk*256 + t; v < N_GN1/4; v += 128*256){
        float4 q = p4[v];
        s  += q.x + q.y + q.z + q.w;
        ss += q.x*q.x + q.y*q.y + q.z*q.z + q.w*q.w;
    }
    #pragma unroll
    for (int off = 32; off; off >>= 1){ s += __shfl_down(s, off); ss += __shfl_down(ss, off); }
    __shared__ float ls[4][2];
    if ((t & 63) == 0){ ls[t>>6][0] = s; ls[t>>6][1] = ss; }
    __syncthreads();
    if (t == 0){
        s  = ls[0][0] + ls[1][0] + ls[2][0] + ls[3][0];
        ss = ls[0][1] + ls[1][1] + ls[2][1] + ls[3][1];
        part[(bg*128 + blk)*2]     = s;
        part[(bg*128 + blk)*2 + 1] = ss;
    }
}

__global__ __launch_bounds__(128) void k_gn1_final(const float* __restrict__ part,
                                                   float* __restrict__ stat){
    const int bg = blockIdx.x, t = threadIdx.x;
    float s  = part[(bg*128 + t)*2];
    float ss = part[(bg*128 + t)*2 + 1];
    #pragma unroll
    for (int off = 32; off; off >>= 1){ s += __shfl_down(s, off); ss += __shfl_down(ss, off); }
    __shared__ float ls[2][2];
    if ((t & 63) == 0){ ls[t>>6][0] = s; ls[t>>6][1] = ss; }
    __syncthreads();
    if (t == 0){
        s  = ls[0][0] + ls[1][0];
        ss = ls[0][1] + ls[1][1];
        float m = s / (float)N_GN1;
        float v = ss / (float)N_GN1 - m*m;
        stat[bg*2]     = m;
        stat[bg*2 + 1] = 1.0f / sqrtf(v + 1e-5f);
    }
}

// ---------------- weight converts ----------------
__global__ __launch_bounds__(256) void k_wcvt(const float* __restrict__ wsrc,
                                              unsigned short* __restrict__ wbf){
    const int co = blockIdx.x;
    const int t = threadIdx.x;
    for (int r = t; r < 896; r += 256){
        int k = r >> 7, c = r & 127;
        wbf[co*896 + r] = f2b(wsrc[co*896 + c*7 + k]);
    }
}

__global__ __launch_bounds__(256) void k_wcvt_mlp(const float* __restrict__ w1,
                                                  const float* __restrict__ w2,
                                                  unsigned short* __restrict__ w1b,
                                                  unsigned short* __restrict__ w2b){
    const int i = blockIdx.x*256 + threadIdx.x;
    if (i < 32768){
        w1b[i] = f2b(w1[i]);
        w2b[i] = f2b(w2[i]);
    }
}

// ---------------- fused MLP + residual (MFMA) ----------------
// grid (1019, 2), 256 thr (4 waves). 64-pixel tile.
__global__ __launch_bounds__(256, 3) void k_mlp(
    const float* __restrict__ x, const float* __restrict__ stat,
    const float* __restrict__ g1, const float* __restrict__ be1,
    const unsigned short* __restrict__ w1b, const float* __restrict__ b1,
    const unsigned short* __restrict__ w2b, const float* __restrict__ b2,
    float* __restrict__ skip, unsigned short* __restrict__ sbf)
{
    __shared__ unsigned short xns[64*128];
    __shared__ unsigned short h1s[64*256];
    __shared__ float aL[128], bL[128];

    const int t = threadIdx.x;
    const int b = blockIdx.y;
    const int pix0 = blockIdx.x * 64;
    const int valid = min(64, HW - pix0);

    const int w  = t >> 6, l = t & 63;
    const int lr = l & 15, lk = l >> 4;

    // GN1 scale/shift LUT
    if (t < 128){
        const int c = t;
        float m = stat[(b*8 + (c >> 4))*2];
        float r = stat[(b*8 + (c >> 4))*2 + 1];
        float a = r * g1[c];
        aL[c] = a;
        bL[c] = be1[c] - m*a;
    }
    __syncthreads();

    { // stage normalized xn tile: thread (p = l, c-block = w*32..+32)
        const int p = l;
        const unsigned sw = ((unsigned)(p & 7)) << 4;
        const float* xb = x + (size_t)b*128*HW + pix0 + p;
        #pragma unroll
        for (int i = 0; i < 8; ++i){
            const int c0 = w*32 + i*4;
            uint2 pk;
            if (p < valid){
                float v0 = __builtin_fmaf(xb[(size_t)(c0+0)*HW], aL[c0+0], bL[c0+0]);
                float v1 = __builtin_fmaf(xb[(size_t)(c0+1)*HW], aL[c0+1], bL[c0+1]);
                float v2 = __builtin_fmaf(xb[(size_t)(c0+2)*HW], aL[c0+2], bL[c0+2]);
                float v3 = __builtin_fmaf(xb[(size_t)(c0+3)*HW], aL[c0+3], bL[c0+3]);
                pk.x = pkbf(v0, v1); pk.y = pkbf(v2, v3);
            } else { pk.x = 0u; pk.y = 0u; }
            *(uint2*)((char*)xns + p*256 + (((unsigned)(c0*2)) ^ sw)) = pk;
        }
    }
    __syncthreads();

    // GEMM1: h1[oc][p] = gelu(w1 @ xn + b1); wave owns oc block w*64..+64
    {
        f32x4 acc[4][4];
        #pragma unroll
        for (int m = 0; m < 4; ++m){
            float4 bv = *(const float4*)(b1 + w*64 + m*16 + lk*4);
            #pragma unroll
            for (int nf = 0; nf < 4; ++nf) acc[m][nf] = __builtin_bit_cast(f32x4, bv);
        }
        const unsigned short* wr = w1b + (size_t)(w*64 + lr)*128 + lk*8;
        #pragma unroll
        for (int ks = 0; ks < 4; ++ks){
            bf16x8 af[4];
            #pragma unroll
            for (int m = 0; m < 4; ++m)
                af[m] = __builtin_bit_cast(bf16x8, *(const uint4*)(wr + m*16*128 + ks*32));
            bf16x8 bfv[4];
            #pragma unroll
            for (int nf = 0; nf < 4; ++nf){
                const int p = nf*16 + lr;
                unsigned off = (unsigned)(p*256)
                             + (((unsigned)(ks*64 + lk*16)) ^ (((unsigned)(p & 7)) << 4));
                bfv[nf] = __builtin_bit_cast(bf16x8, *(const uint4*)((const char*)xns + off));
            }
            #pragma unroll
            for (int m = 0; m < 4; ++m)
                #pragma unroll
                for (int nf = 0; nf < 4; ++nf)
                    acc[m][nf] = __builtin_amdgcn_mfma_f32_16x16x32_bf16(af[m], bfv[nf], acc[m][nf], 0, 0, 0);
        }
        #pragma unroll
        for (int m = 0; m < 4; ++m){
            const int oc0 = w*64 + m*16 + lk*4;
            #pragma unroll
            for (int nf = 0; nf < 4; ++nf){
                const int p = nf*16 + lr;
                uint2 pk;
                pk.x = pkbf(gelu_f(acc[m][nf][0]), gelu_f(acc[m][nf][1]));
                pk.y = pkbf(gelu_f(acc[m][nf][2]), gelu_f(acc[m][nf][3]));
                unsigned off = (unsigned)(p*512)
                             + (((unsigned)(oc0*2)) ^ (((unsigned)(p & 7)) << 4));
                *(uint2*)((char*)h1s + off) = pk;
            }
        }
    }
    __syncthreads();

    // GEMM2 (swapped): C[p][c] = h1^T @ w2^T + b2 + x.
    // A-frag = h1 rows (p), B-frag = w2b rows (c) — identical reads to round 5,
    // but p lands on the register axis => float4 stores/loads along p.
    {
        f32x4 acc[4][2];
        const float bv0 = b2[w*32 + lr];
        const float bv1 = b2[w*32 + 16 + lr];
        #pragma unroll
        for (int pm = 0; pm < 4; ++pm){
            acc[pm][0] = (f32x4)bv0;
            acc[pm][1] = (f32x4)bv1;
        }
        const unsigned short* wr = w2b + (size_t)(w*32 + lr)*256 + lk*8;
        #pragma unroll
        for (int ks = 0; ks < 8; ++ks){
            bf16x8 bfw[2];
            #pragma unroll
            for (int cn = 0; cn < 2; ++cn)
                bfw[cn] = __builtin_bit_cast(bf16x8, *(const uint4*)(wr + cn*16*256 + ks*32));
            bf16x8 afh[4];
            #pragma unroll
            for (int pm = 0; pm < 4; ++pm){
                const int p = pm*16 + lr;
                unsigned off = (unsigned)(p*512)
                             + (((unsigned)(ks*64 + lk*16)) ^ (((unsigned)(p & 7)) << 4));
                afh[pm] = __builtin_bit_cast(bf16x8, *(const uint4*)((const char*)h1s + off));
            }
            #pragma unroll
            for (int pm = 0; pm < 4; ++pm)
                #pragma unroll
                for (int cn = 0; cn < 2; ++cn)
                    acc[pm][cn] = __builtin_amdgcn_mfma_f32_16x16x32_bf16(afh[pm], bfw[cn], acc[pm][cn], 0, 0, 0);
        }
        // epilogue: float4 residual + store; scalar u16 sbf stores
        #pragma unroll
        for (int pm = 0; pm < 4; ++pm){
            const int p0 = pm*16 + lk*4;
            if (p0 < valid){                     // valid is a multiple of 4 (tail = 8)
                #pragma unroll
                for (int cn = 0; cn < 2; ++cn){
                    const int c = w*32 + cn*16 + lr;
                    size_t base = (size_t)(b*128 + c)*HW + pix0 + p0;
                    float4 xv = *(const float4*)(x + base);
                    float4 o;
                    o.x = acc[pm][cn][0] + xv.x; o.y = acc[pm][cn][1] + xv.y;
                    o.z = acc[pm][cn][2] + xv.z; o.w = acc[pm][cn][3] + xv.w;
                    *(float4*)(skip + base) = o;
                    if (sbf){
                        unsigned short* sp = sbf + ((size_t)b*HW + pix0 + p0)*128 + c;
                        sp[0]   = f2b(o.x);
                        sp[128] = f2b(o.y);
                        sp[256] = f2b(o.z);
                        sp[384] = f2b(o.w);
                    }
                }
            }
        }
    }
}

// ---------------- Y build: gather + psi reduce -> Y_t[n][ck] bf16 ----------------
// grid (6 wo-tiles of 32, 91 ho, 2 b), 256 thr = 32 wol x 8 cq.
__global__ __launch_bounds__(256) void k_ybuild(
    const unsigned short* __restrict__ sbf,
    const float* __restrict__ psi_v, const int* __restrict__ psi_hi, const int* __restrict__ psi_wi,
    unsigned short* __restrict__ Yt)
{
    __shared__ int   offh[16];
    __shared__ int   wis[16];
    __shared__ float psis[112];

    const int t   = threadIdx.x;
    const int wot = blockIdx.x, ho = blockIdx.y, b = blockIdx.z;

    if (t < 112) psis[t] = psi_v[((t >> 4)*HOUT + ho)*NNZ + (t & 15)];
    if (t < 16){ offh[t] = psi_hi[ho*NNZ + t] * WIN; wis[t] = psi_wi[ho*NNZ + t]; }
    __syncthreads();

    const int wol = t >> 3, cq = t & 7;
    const int wo  = wot*32 + wol;
    const bool valid = (wo < WOUT);
    const int wo_c = valid ? wo : (WOUT - 1);

    int offs[16];
    #pragma unroll
    for (int n = 0; n < 16; ++n){
        int wv = wis[n] + 2*wo_c;
        wv = (wv >= WIN) ? (wv - WIN) : wv;
        offs[n] = offh[n] + wv;
    }

    const unsigned short* sb = sbf + (size_t)b * HW * 128;
    unsigned short* yrow = Yt + (size_t)(b*NPB + ho*WOUT + wo_c) * 896;

    #pragma unroll 1
    for (int cc = 0; cc < 4; ++cc){
        const int c0 = cc*32 + cq*4;
        float ya[4][7];
        #pragma unroll
        for (int ci = 0; ci < 4; ++ci)
            #pragma unroll
            for (int k = 0; k < 7; ++k) ya[ci][k] = 0.f;

        #pragma unroll 2
        for (int n = 0; n < 16; ++n){
            uint2 q = *(const uint2*)(sb + (size_t)offs[n]*128 + c0);
            float g0 = blo(q.x), g1 = bhi(q.x), g2 = blo(q.y), g3 = bhi(q.y);
            #pragma unroll
            for (int k = 0; k < 7; ++k){
                float pv = psis[k*16 + n];
                ya[0][k] += pv*g0; ya[1][k] += pv*g1;
                ya[2][k] += pv*g2; ya[3][k] += pv*g3;
            }
        }
        if (valid){
            #pragma unroll
            for (int k = 0; k < 7; ++k){
                uint2 pk;
                pk.x = pkbf(ya[0][k], ya[1][k]);
                pk.y = pkbf(ya[2][k], ya[3][k]);
                *(uint2*)(yrow + k*128 + c0) = pk;
            }
        }
    }
}

// ---------------- DISCO GEMM: D[n][co] = Y_t @ W^T, no LDS ----------------
// Output stored bf16 (xdb); GN2 partials from fp32 accs.
__global__ __launch_bounds__(256) void k_dgemm(
    const unsigned short* __restrict__ Yt, const unsigned short* __restrict__ wbf,
    const float* __restrict__ bias,
    unsigned short* __restrict__ xdb, float* __restrict__ part)
{
    const int flat = blockIdx.x + 128*(blockIdx.y + 2*blockIdx.z);
    const int rem  = (flat & 7)*64 + (flat >> 3);
    const int coh  = rem & 1;
    const int nt   = (rem >> 1) & 127;
    const int b    = rem >> 8;

    const int t = threadIdx.x;
    const int w = t >> 6, l = t & 63;
    const int lr = l & 15, lk = l >> 4;
    const int wn2 = w >> 1, wc = w & 1;

    const int n0  = nt*128 + wn2*64;
    const int co0 = coh*128 + wc*64;

    const unsigned short* pa[4];
    const unsigned short* pb[4];
    #pragma unroll
    for (int i = 0; i < 4; ++i)
        pa[i] = Yt + (size_t)(b*NPB + n0 + i*16 + lr)*896 + lk*8;
    #pragma unroll
    for (int j = 0; j < 4; ++j)
        pb[j] = wbf + (size_t)(co0 + j*16 + lr)*896 + lk*8;

    f32x4 acc[4][4];
    #pragma unroll
    for (int i = 0; i < 4; ++i)
        #pragma unroll
        for (int j = 0; j < 4; ++j) acc[i][j] = (f32x4)0.f;

    #pragma unroll 2
    for (int ks = 0; ks < 28; ++ks){
        bf16x8 af[4], bf[4];
        #pragma unroll
        for (int i = 0; i < 4; ++i)
            af[i] = __builtin_bit_cast(bf16x8, *(const uint4*)(pa[i] + ks*32));
        #pragma unroll
        for (int j = 0; j < 4; ++j)
            bf[j] = __builtin_bit_cast(bf16x8, *(const uint4*)(pb[j] + ks*32));
        #pragma unroll
        for (int i = 0; i < 4; ++i)
            #pragma unroll
            for (int j = 0; j < 4; ++j)
                acc[i][j] = __builtin_amdgcn_mfma_f32_16x16x32_bf16(af[i], bf[j], acc[i][j], 0, 0, 0);
    }

    float s[2] = {0.f, 0.f}, ss[2] = {0.f, 0.f};
    #pragma unroll
    for (int j = 0; j < 4; ++j){
        const int co = co0 + j*16 + lr;
        const float bv = bias[co];
        unsigned short* outp = xdb + (size_t)(b*256 + co)*NPB;
        const int jp = j >> 1;
        #pragma unroll
        for (int i = 0; i < 4; ++i){
            const int nb = n0 + i*16 + lk*4;
            if (nb < NPB){
                float o0 = acc[i][j][0] + bv, o1 = acc[i][j][1] + bv;
                float o2 = acc[i][j][2] + bv, o3 = acc[i][j][3] + bv;
                uint2 pk; pk.x = pkbf(o0, o1); pk.y = pkbf(o2, o3);
                *(uint2*)(outp + nb) = pk;
                s[jp]  += o0 + o1 + o2 + o3;
                ss[jp] += o0*o0 + o1*o1 + o2*o2 + o3*o3;
            }
        }
    }
    #pragma unroll
    for (int off = 32; off; off >>= 1){
        s[0] += __shfl_down(s[0], off); ss[0] += __shfl_down(ss[0], off);
        s[1] += __shfl_down(s[1], off); ss[1] += __shfl_down(ss[1], off);
    }
    if (l == 0){
        const int bid = (b*2 + coh)*128 + nt;
        part[(bid*8 + w*2 + 0)*2]     = s[0];
        part[(bid*8 + w*2 + 0)*2 + 1] = ss[0];
        part[(bid*8 + w*2 + 1)*2]     = s[1];
        part[(bid*8 + w*2 + 1)*2 + 1] = ss[1];
    }
}

// ---------------- GN2 finalize (split path) ----------------
__global__ __launch_bounds__(256) void k_gn2_final_s(const float* __restrict__ part,
                                                     float* __restrict__ stat){
    const int bg = blockIdx.x, b = bg >> 3, g = bg & 7, t = threadIdx.x;
    const int coh = g >> 2, wc = (g >> 1) & 1, jp = g & 1;
    const int nt = t & 127, wn2 = t >> 7;
    const int bid = (b*2 + coh)*128 + nt;
    const int slot = (wn2*2 + wc)*2 + jp;
    float s  = part[(bid*8 + slot)*2];
    float ss = part[(bid*8 + slot)*2 + 1];
    #pragma unroll
    for (int off = 32; off; off >>= 1){ s += __shfl_down(s, off); ss += __shfl_down(ss, off); }
    __shared__ float ls[4][2];
    if ((t & 63) == 0){ ls[t>>6][0] = s; ls[t>>6][1] = ss; }
    __syncthreads();
    if (t == 0){
        s  = ls[0][0] + ls[1][0] + ls[2][0] + ls[3][0];
        ss = ls[0][1] + ls[1][1] + ls[2][1] + ls[3][1];
        float m = s / (float)N_GN2;
        float v = ss / (float)N_GN2 - m*m;
        stat[bg*2]     = m;
        stat[bg*2 + 1] = 1.0f / sqrtf(v + 1e-5f);
    }
}

// ---------------- GN2 apply + gelu: bf16 in -> fp32 out (split path) ----------------
__global__ __launch_bounds__(256) void k_gn2_apply_s(const unsigned short* __restrict__ xdb,
                                                     float* __restrict__ outd,
                                                     const float* __restrict__ stat,
                                                     const float* __restrict__ g2a,
                                                     const float* __restrict__ be2){
    const int gid = blockIdx.x*256 + threadIdx.x;
    const int stride = gridDim.x*256;
    for (int v = gid; v < 2096640; v += stride){
        uint2 q = ((const uint2*)xdb)[v];
        int i  = v << 2;
        int bc = i / 16380;
        int co = bc & 255, b = bc >> 8;
        float m  = stat[(b*8 + (co >> 5))*2];
        float r  = stat[(b*8 + (co >> 5))*2 + 1];
        float a  = r * g2a[co];
        float bb = be2[co] - m*a;
        float4 o;
        o.x = gelu_f(__builtin_fmaf(blo(q.x), a, bb));
        o.y = gelu_f(__builtin_fmaf(bhi(q.x), a, bb));
        o.z = gelu_f(__builtin_fmaf(blo(q.y), a, bb));
        o.w = gelu_f(__builtin_fmaf(bhi(q.y), a, bb));
        ((float4*)outd)[v] = o;
    }
}

// ================= FALLBACK (fused disco, fp32 in-place apply) =================
__global__ __launch_bounds__(256, 2) void k_disco_fb(
    const float* __restrict__ skip,
    const float* __restrict__ psi_v, const int* __restrict__ psi_hi, const int* __restrict__ psi_wi,
    const unsigned short* __restrict__ wbf, const float* __restrict__ bias,
    float* __restrict__ xdown, float* __restrict__ part)
{
    __shared__ unsigned short yT[96*256];

    const int t   = threadIdx.x;
    const int woh = blockIdx.x;
    const int ho  = blockIdx.y;
    const int z   = blockIdx.z;
    const int b   = z >> 1, coh = z & 1;
    const int co0 = coh * 128;
    const int wo0 = woh * 90;

    const int w  = t >> 6;
    const int l  = t & 63;
    const int wm = w >> 1, wn = w & 1;

    const int wol = t & 31;
    const int cq  = t >> 5;
    const unsigned sw = (unsigned)(wol & 7) << 4;

    const float* skipb = skip + (size_t)b * (128*HW);

    f32x4 acc[4][3];
    #pragma unroll
    for (int m = 0; m < 4; ++m)
        #pragma unroll
        for (int nf = 0; nf < 3; ++nf) acc[m][nf] = (f32x4)0.f;

    #pragma unroll 1
    for (int cc = 0; cc < 4; ++cc){
        __syncthreads();
        const float* bp0 = skipb + (size_t)(cc*32 + cq*4 + 0)*HW;
        const float* bp1 = skipb + (size_t)(cc*32 + cq*4 + 1)*HW;
        const float* bp2 = skipb + (size_t)(cc*32 + cq*4 + 2)*HW;
        const float* bp3 = skipb + (size_t)(cc*32 + cq*4 + 3)*HW;

        float ya[3][4][7];
        #pragma unroll
        for (int wj = 0; wj < 3; ++wj)
            #pragma unroll
            for (int ci = 0; ci < 4; ++ci)
                #pragma unroll
                for (int k = 0; k < 7; ++k) ya[wj][ci][k] = 0.f;

        #pragma unroll 2
        for (int n = 0; n < NNZ; ++n){
            const int hi = psi_hi[ho*NNZ + n];
            const int wi = psi_wi[ho*NNZ + n];
            float ps[7];
            #pragma unroll
            for (int k = 0; k < 7; ++k) ps[k] = psi_v[(k*HOUT + ho)*NNZ + n];
            const int rowb = hi * WIN;
            #pragma unroll
            for (int wj = 0; wj < 3; ++wj){
                int wv = wi + 2*(wo0 + wol + 32*wj);
                wv = (wv >= 720) ? (wv - 720) : (wv >= 360 ? (wv - 360) : wv);
                const int off = rowb + wv;
                float g0 = bp0[off], g1 = bp1[off], g2 = bp2[off], g3 = bp3[off];
                #pragma unroll
                for (int k = 0; k < 7; ++k){
                    float pv = ps[k];
                    ya[wj][0][k] += pv*g0; ya[wj][1][k] += pv*g1;
                    ya[wj][2][k] += pv*g2; ya[wj][3][k] += pv*g3;
                }
            }
        }
        #pragma unroll
        for (int wj = 0; wj < 3; ++wj){
            char* row = (char*)yT + (wol + 32*wj)*512;
            #pragma unroll
            for (int k = 0; k < 7; ++k){
                unsigned base = ((unsigned)(k*64 + cq*8)) ^ sw;
                *(unsigned*)(row + base)     = pkbf(ya[wj][0][k], ya[wj][1][k]);
                *(unsigned*)(row + base + 4) = pkbf(ya[wj][2][k], ya[wj][3][k]);
            }
        }
        __syncthreads();

        const unsigned short* wrow = wbf + (size_t)(co0 + wm*64 + (l & 15))*896
                                         + cc*32 + ((l >> 4) << 3);
        #pragma unroll
        for (int k = 0; k < 7; ++k){
            bf16x8 af[4];
            #pragma unroll
            for (int m = 0; m < 4; ++m)
                af[m] = __builtin_bit_cast(bf16x8,
                          *(const uint4*)(wrow + (size_t)m*16*896 + k*128));
            bf16x8 bfv[3];
            #pragma unroll
            for (int nf = 0; nf < 3; ++nf){
                const int wo_l = wn*48 + nf*16 + (l & 15);
                unsigned off = (unsigned)(wo_l*512)
                             + (((unsigned)(k*64) + ((unsigned)(l >> 4) << 4))
                                ^ ((unsigned)(wo_l & 7) << 4));
                bfv[nf] = __builtin_bit_cast(bf16x8, *(const uint4*)((const char*)yT + off));
            }
            #pragma unroll
            for (int m = 0; m < 4; ++m)
                #pragma unroll
                for (int nf = 0; nf < 3; ++nf)
                    acc[m][nf] = __builtin_amdgcn_mfma_f32_16x16x32_bf16(af[m], bfv[nf], acc[m][nf], 0, 0, 0);
        }
    }

    float s[2] = {0.f, 0.f}, ss[2] = {0.f, 0.f};
    #pragma unroll
    for (int m = 0; m < 4; ++m){
        const int pair = m >> 1;
        const int cob = co0 + wm*64 + m*16 + ((l >> 4) << 2);
        float4 bv = *(const float4*)(bias + cob);
        #pragma unroll
        for (int nf = 0; nf < 3; ++nf){
            const int wo_t = wn*48 + nf*16 + (l & 15);
            if (wo_t < 90){
                #pragma unroll
                for (int r = 0; r < 4; ++r){
                    float v = acc[m][nf][r] + ((const float*)&bv)[r];
                    xdown[((size_t)(b*256 + cob + r)*HOUT + ho)*WOUT + wo0 + wo_t] = v;
                    s[pair] += v; ss[pair] += v*v;
                }
            }
        }
    }
    #pragma unroll
    for (int off = 32; off; off >>= 1){
        s[0] += __shfl_down(s[0], off); ss[0] += __shfl_down(ss[0], off);
        s[1] += __shfl_down(s[1], off); ss[1] += __shfl_down(ss[1], off);
    }
    if (l == 0){
        const int tid = (z*91 + ho)*2 + woh;
        part[(tid*8 + w*2 + 0)*2]     = s[0];
        part[(tid*8 + w*2 + 0)*2 + 1] = ss[0];
        part[(tid*8 + w*2 + 1)*2]     = s[1];
        part[(tid*8 + w*2 + 1)*2 + 1] = ss[1];
    }
}

__global__ __launch_bounds__(256) void k_gn2_final_fb(const float* __restrict__ part,
                                                      float* __restrict__ stat){
    const int bg = blockIdx.x, b = bg >> 3, g = bg & 7, t = threadIdx.x;
    const int coh = g >> 2, gl = g & 3, wm = gl >> 1, pair = gl & 1;
    float s = 0.f, ss = 0.f;
    for (int i = t; i < 364; i += 256){
        int ho = i >> 2, r = i & 3, woh = r >> 1, wn = r & 1;
        int tid = (((b*2 + coh)*91 + ho)*2 + woh);
        int slot = (wm*2 + wn)*2 + pair;
        s  += part[(tid*8 + slot)*2];
        ss += part[(tid*8 + slot)*2 + 1];
    }
    #pragma unroll
    for (int off = 32; off; off >>= 1){ s += __shfl_down(s, off); ss += __shfl_down(ss, off); }
    __shared__ float ls[4][2];
    if ((t & 63) == 0){ ls[t>>6][0] = s; ls[t>>6][1] = ss; }
    __syncthreads();
    if (t == 0){
        s  = ls[0][0] + ls[1][0] + ls[2][0] + ls[3][0];
        ss = ls[0][1] + ls[1][1] + ls[2][1] + ls[3][1];
        float m = s / (float)N_GN2;
        float v = ss / (float)N_GN2 - m*m;
        stat[bg*2]     = m;
        stat[bg*2 + 1] = 1.0f / sqrtf(v + 1e-5f);
    }
}

__global__ __launch_bounds__(256) void k_gn2_apply(float* __restrict__ xd,
                                                   const float* __restrict__ stat,
                                                   const float* __restrict__ g2a,
                                                   const float* __restrict__ be2){
    const int gid = blockIdx.x*256 + threadIdx.x;
    const int stride = gridDim.x*256;
    for (int v = gid; v < 2096640; v += stride){
        float4 q = ((float4*)xd)[v];
        int i  = v << 2;
        int bc = i / 16380;
        int co = bc & 255, b = bc >> 8;
        float m  = stat[(b*8 + (co >> 5))*2];
        float r  = stat[(b*8 + (co >> 5))*2 + 1];
        float a  = r * g2a[co];
        float bb = be2[co] - m*a;
        q.x = gelu_f(__builtin_fmaf(q.x, a, bb));
        q.y = gelu_f(__builtin_fmaf(q.y, a, bb));
        q.z = gelu_f(__builtin_fmaf(q.z, a, bb));
        q.w = gelu_f(__builtin_fmaf(q.w, a, bb));
        ((float4*)xd)[v] = q;
    }
}

extern "C" void kernel_launch(void* const* d_in, const int* in_sizes, int n_in,
                              void* d_out, int out_size, void* d_ws, size_t ws_size,
                              hipStream_t stream){
    const float* x      = (const float*)d_in[0];
    const float* psi_v  = (const float*)d_in[1];
    const int*   psi_hi = (const int*)d_in[2];
    const int*   psi_wi = (const int*)d_in[3];
    const float* weight = (const float*)d_in[4];
    const float* bias   = (const float*)d_in[5];
    const float* g1     = (const float*)d_in[6];
    const float* be1    = (const float*)d_in[7];
    const float* w1     = (const float*)d_in[8];
    const float* b1     = (const float*)d_in[9];
    const float* w2     = (const float*)d_in[10];
    const float* b2     = (const float*)d_in[11];
    const float* g2     = (const float*)d_in[12];
    const float* be2    = (const float*)d_in[13];

    float* skip  = (float*)d_out;
    float* xdown = skip + 16680960;          // 2*128*181*360

    float* ws       = (float*)d_ws;
    float* gn1_part = ws;                    // 4096 f
    float* gn1_stat = ws + 4096;             // 32
    float* gn2_part = ws + 4128;             // 11648
    float* gn2_stat = ws + 15776;            // 32
    unsigned short* wbf = (unsigned short*)(ws + 15808);   // 229376 us
    unsigned short* w1b = (unsigned short*)(ws + 130496);  // 32768 us
    unsigned short* w2b = (unsigned short*)(ws + 146880);  // 32768 us
    unsigned short* sbf = (unsigned short*)(ws + 163264);  // 16,680,960 us (dead after ybuild)
    unsigned short* xdb = sbf;                             // overlay: 8,386,560 us
    unsigned short* Yt  = (unsigned short*)(ws + 8503744); // 29,360,128 us
    const size_t need = (8503744ull + 14680064ull) * 4ull; // ~92.7 MB

    const bool split = (ws_size >= need);

    k_gn1_partial<<<dim3(128, 16), 256, 0, stream>>>(x, gn1_part);
    k_gn1_final  <<<16, 128, 0, stream>>>(gn1_part, gn1_stat);
    k_wcvt       <<<256, 256, 0, stream>>>(weight, wbf);
    k_wcvt_mlp   <<<128, 256, 0, stream>>>(w1, w2, w1b, w2b);
    k_mlp        <<<dim3(1019, 2), 256, 0, stream>>>(x, gn1_stat, g1, be1, w1b, b1, w2b, b2,
                                                     skip, split ? sbf : (unsigned short*)nullptr);
    if (split){
        k_ybuild   <<<dim3(6, 91, 2), 256, 0, stream>>>(sbf, psi_v, psi_hi, psi_wi, Yt);
        k_dgemm    <<<dim3(128, 2, 2), 256, 0, stream>>>(Yt, wbf, bias, xdb, gn2_part);
        k_gn2_final_s<<<16, 256, 0, stream>>>(gn2_part, gn2_stat);
        k_gn2_apply_s<<<2048, 256, 0, stream>>>(xdb, xdown, gn2_stat, g2, be2);
    } else {
        k_disco_fb <<<dim3(2, 91, 4), 256, 0, stream>>>(skip, psi_v, psi_hi, psi_wi,
                                                        wbf, bias, xdown, gn2_part);
        k_gn2_final_fb<<<16, 256, 0, stream>>>(gn2_part, gn2_stat);
        k_gn2_apply<<<2048, 256, 0, stream>>>(xdown, gn2_stat, g2, be2);
    }
}